// Round 12
// baseline (354.124 us; speedup 1.0000x reference)
//
#include <hip/hip_runtime.h>
#include <math.h>

#define NB 2048
#define PM_STAGE 2097152   // elements per pmeans stage (2048*16*2*32)
#define BPK_L    81920     // elements per packed weight layer (10*16*64*8)
#define MBK_L    131072    // elements per packed mean-W layer (16*16*64*8)

typedef float    f32x4 __attribute__((ext_vector_type(4)));
typedef _Float16 f16x8 __attribute__((ext_vector_type(8)));
typedef _Float16 f16x4 __attribute__((ext_vector_type(4)));

__device__ __forceinline__ float fast_tanh(float x) {
    float ax = fabsf(x);
    float e  = __expf(2.0f * ax);
    float t  = 1.0f - 2.0f / (e + 1.0f);
    return copysignf(t, x);
}

__device__ __forceinline__ void split16(float x, _Float16& hi, _Float16& lo) {
    hi = (_Float16)x;
    lo = (_Float16)(x - (float)hi);
}

// ---------------------------------------------------------------------------
// MERGED one-time weight packs (single dispatch). (R11-verbatim, verified)
// ---------------------------------------------------------------------------
__global__ __launch_bounds__(256) void k_prep_all(
    const float* __restrict__ sW, const float* __restrict__ vW,
    const float* __restrict__ pW,
    const float* __restrict__ wuW, const float* __restrict__ wdW,
    _Float16* __restrict__ Bhi, _Float16* __restrict__ Blo,
    _Float16* __restrict__ pBhi, _Float16* __restrict__ pBlo,
    _Float16* __restrict__ oBhi, _Float16* __restrict__ oBlo,
    _Float16* __restrict__ mBhi, _Float16* __restrict__ mBlo)
{
    const int blk  = blockIdx.x;
    const int lane = threadIdx.x & 63;
    const int sub  = threadIdx.x >> 6;

    if (blk < 50) {
        const int l  = blk / 10;
        const int kc = blk % 10;
        const float* Wsrc = (l < 4) ? (sW + (size_t)l * 212992) : vW;
        const size_t base = (size_t)l * BPK_L + (size_t)kc * 8192;
#pragma unroll
        for (int ntl = 0; ntl < 4; ++ntl) {
            const int nt = sub * 4 + ntl;
            const int n  = nt * 16 + (lane & 15);
#pragma unroll
            for (int j = 0; j < 8; ++j) {
                const int f = kc * 32 + (lane >> 4) * 8 + j;   // 0..319
                int row;
                if (f < 256)      row = f;
                else if (f < 288) row = 768 + (f - 256);
                else              row = 800 + (f - 288);
                const float w = Wsrc[row * 256 + n];
                _Float16 hi, lo; split16(w, hi, lo);
                Bhi[base + (size_t)(nt * 64 + lane) * 8 + j] = hi;
                Blo[base + (size_t)(nt * 64 + lane) * 8 + j] = lo;
            }
        }
    } else if (blk < 54) {
        if (threadIdx.x < 128) {
            const int l   = blk - 50;
            const int nt  = threadIdx.x >> 6;
            const int m16 = lane & 15, quad = lane >> 4;
#pragma unroll
            for (int j = 0; j < 8; ++j) {
                float w = pW[l * 1024 + (quad * 8 + j) * 32 + nt * 16 + m16];
                _Float16 hi, lo; split16(w, hi, lo);
                pBhi[((size_t)l * 2 + nt) * 512 + lane * 8 + j] = hi;
                pBlo[((size_t)l * 2 + nt) * 512 + lane * 8 + j] = lo;
            }
        }
    } else if (blk < 70) {
        const int ob   = blk - 54;       // spin*8 + kc
        const int spin = ob >> 3, kc = ob & 7;
        const float* W = spin ? wdW : wuW;
#pragma unroll
        for (int t = 0; t < 2; ++t) {
            const int nt = sub * 2 + t;
            const int n  = nt * 16 + (lane & 15);
#pragma unroll
            for (int j = 0; j < 8; ++j) {
                const int k = kc * 32 + (lane >> 4) * 8 + j;
                float w = W[k * 128 + n];
                _Float16 hi, lo; split16(w, hi, lo);
                const size_t o = (((size_t)spin * 8 + kc) * 8 + nt) * 512 + (size_t)lane * 8 + j;
                oBhi[o] = hi; oBlo[o] = lo;
            }
        }
    } else {
        const int mb = blk - 70;         // l*16 + kk
        const int l  = mb >> 4;
        const int kk = mb & 15;          // hh*8 + kc
        const float* Wsrc = (l < 4) ? (sW + (size_t)l * 212992) : vW;
        const size_t base = (size_t)l * MBK_L + (size_t)kk * 8192;
#pragma unroll
        for (int ntl = 0; ntl < 4; ++ntl) {
            const int nt = sub * 4 + ntl;
            const int n  = nt * 16 + (lane & 15);
#pragma unroll
            for (int j = 0; j < 8; ++j) {
                const int row = 256 + kk * 32 + (lane >> 4) * 8 + j;
                const float w = Wsrc[row * 256 + n];
                _Float16 hi, lo; split16(w, hi, lo);
                mBhi[base + (size_t)(nt * 64 + lane) * 8 + j] = hi;
                mBlo[base + (size_t)(nt * 64 + lane) * 8 + j] = lo;
            }
        }
    }
}

// ---------------------------------------------------------------------------
// p-stream via split-f16 MFMA (3-term), barrier-free (R1-verbatim, verified).
// ---------------------------------------------------------------------------
__global__ __launch_bounds__(256) void k_pstream(
    const float* __restrict__ r,
    const float* __restrict__ pW0, const float* __restrict__ pb0,
    const float* __restrict__ pb,
    const _Float16* __restrict__ pBhi, const _Float16* __restrict__ pBlo,
    _Float16* __restrict__ pm_hi, _Float16* __restrict__ pm_lo)
{
    const int b    = blockIdx.x >> 2;
    const int jg   = blockIdx.x & 3;
    const int tid  = threadIdx.x;
    const int lane = tid & 63;
    const int wvl  = tid >> 6;           // 0..3
    const int j    = jg * 4 + wvl;       // this wave's j column (0..15)
    const int m16  = lane & 15;
    const int quad = lane >> 4;

    __shared__ float rl[48];
    __shared__ float pst[4][32][17];     // wave-private slices, stride 17 (odd)

    if (tid < 48) rl[tid] = r[b * 48 + tid];
    __syncthreads();                     // only barrier in the kernel

    const float rjx = rl[j * 3 + 0];
    const float rjy = rl[j * 3 + 1];
    const float rjz = rl[j * 3 + 2];

    const int f0 = m16, f1 = m16 + 16;
    float pcur[2][4];   // [nt][reg], D-layout residual state (rows i = quad*4+reg)

    // ---- layer 0
#pragma unroll
    for (int reg = 0; reg < 4; ++reg) {
        const int i = quad * 4 + reg;
        float dx = rjx - rl[i * 3 + 0];
        float dy = rjy - rl[i * 3 + 1];
        float dz = rjz - rl[i * 3 + 2];
        float ee = (i == j) ? 1.0f : 0.0f;
        float len = sqrtf((dx + ee) * (dx + ee) + (dy + ee) * (dy + ee) + (dz + ee) * (dz + ee));
#pragma unroll
        for (int nt = 0; nt < 2; ++nt) {
            const int k = nt ? f1 : f0;
            float acc = pb0[k] + dx * pW0[k] + dy * pW0[32 + k]
                      + dz * pW0[64 + k] + len * pW0[96 + k];
            float v = fast_tanh(acc);
            pcur[nt][reg] = v;
            pst[wvl][k][i] = v;
        }
    }
    asm volatile("s_waitcnt lgkmcnt(0)" ::: "memory");

    // ---- stage-0 means
    {
        const int mh = lane >> 5, mk = lane & 31;
        float s = 0.f;
#pragma unroll
        for (int i8 = 0; i8 < 8; ++i8) s += pst[wvl][mk][mh * 8 + i8];
        _Float16 hi, lo; split16(s * 0.125f, hi, lo);
        const size_t o = (size_t)b * 1024 + j * 64 + lane;
        pm_hi[o] = hi;
        pm_lo[o] = lo;
    }

    for (int l = 0; l < 4; ++l) {
        f16x8 ah, al;
#pragma unroll
        for (int jj = 0; jj < 8; ++jj) {
            float v = pst[wvl][quad * 8 + jj][m16];
            _Float16 hi, lo; split16(v, hi, lo);
            ah[jj] = hi; al[jj] = lo;
        }
        const _Float16* bhp = pBhi + ((size_t)l * 2) * 512 + (size_t)lane * 8;
        const _Float16* blp = pBlo + ((size_t)l * 2) * 512 + (size_t)lane * 8;
        f32x4 acc0 = (f32x4){0.f, 0.f, 0.f, 0.f};
        f32x4 acc1 = (f32x4){0.f, 0.f, 0.f, 0.f};
        {
            f16x8 bh = *(const f16x8*)(bhp);
            f16x8 bl = *(const f16x8*)(blp);
            acc0 = __builtin_amdgcn_mfma_f32_16x16x32_f16(ah, bh, acc0, 0, 0, 0);
            acc0 = __builtin_amdgcn_mfma_f32_16x16x32_f16(ah, bl, acc0, 0, 0, 0);
            acc0 = __builtin_amdgcn_mfma_f32_16x16x32_f16(al, bh, acc0, 0, 0, 0);
            bh = *(const f16x8*)(bhp + 512);
            bl = *(const f16x8*)(blp + 512);
            acc1 = __builtin_amdgcn_mfma_f32_16x16x32_f16(ah, bh, acc1, 0, 0, 0);
            acc1 = __builtin_amdgcn_mfma_f32_16x16x32_f16(ah, bl, acc1, 0, 0, 0);
            acc1 = __builtin_amdgcn_mfma_f32_16x16x32_f16(al, bh, acc1, 0, 0, 0);
        }
        const float b0v = pb[l * 32 + f0];
        const float b1v = pb[l * 32 + f1];
        asm volatile("" ::: "memory");
#pragma unroll
        for (int reg = 0; reg < 4; ++reg) {
            const int i = quad * 4 + reg;
            pcur[0][reg] += fast_tanh(acc0[reg] + b0v);
            pcur[1][reg] += fast_tanh(acc1[reg] + b1v);
            pst[wvl][f0][i] = pcur[0][reg];
            pst[wvl][f1][i] = pcur[1][reg];
        }
        asm volatile("s_waitcnt lgkmcnt(0)" ::: "memory");
        {
            const int mh = lane >> 5, mk = lane & 31;
            float s = 0.f;
#pragma unroll
            for (int i8 = 0; i8 < 8; ++i8) s += pst[wvl][mk][mh * 8 + i8];
            _Float16 hi, lo; split16(s * 0.125f, hi, lo);
            const size_t o = (size_t)(l + 1) * PM_STAGE + (size_t)b * 1024 + j * 64 + lane;
            pm_hi[o] = hi;
            pm_lo[o] = lo;
        }
    }
}

// ---------------------------------------------------------------------------
__device__ __forceinline__ void slogdet8(float M[8][8], float& sgn_out, float& ld_out) {
    float sgn = 1.f, ld = 0.f;
#pragma unroll
    for (int k = 0; k < 8; ++k) {
        float best = fabsf(M[k][k]);
        int p = k;
#pragma unroll
        for (int rr = k + 1; rr < 8; ++rr) {
            float v = fabsf(M[rr][k]);
            if (v > best) { best = v; p = rr; }
        }
        if (p != k) sgn = -sgn;
#pragma unroll
        for (int rr = k + 1; rr < 8; ++rr) {
            bool sw = (rr == p);
#pragma unroll
            for (int cc = k; cc < 8; ++cc) {
                float x = M[k][cc], y = M[rr][cc];
                M[k][cc]  = sw ? y : x;
                M[rr][cc] = sw ? x : y;
            }
        }
        float piv = M[k][k];
        if (piv < 0.f) sgn = -sgn;
        ld += logf(fabsf(piv));
        float inv = 1.f / piv;
#pragma unroll
        for (int rr = k + 1; rr < 8; ++rr) {
            float f = M[rr][k] * inv;
#pragma unroll
            for (int cc = k + 1; cc < 8; ++cc) M[rr][cc] -= f * M[k][cc];
        }
    }
    sgn_out = sgn; ld_out = ld;
}

// ---------------------------------------------------------------------------
// MEGA v11: v10 + (1) residual carried in REGISTERS across layers (resv —
// the epilogue thread's positions repeat every layer, so the residual equals
// the t it computed last layer; removes 64 LDS u16 reads + ~96 VALU from the
// post-B2 serial section per layer; init from LDS once so layer 0 matches),
// (2) mean-GEMM accumulator split into mu/md chains (halves the 48-deep
// serial MFMA dependency), summed at the Z write (fp32-order change ~1e-7).
// ---------------------------------------------------------------------------
#define SROW 264
#define MROW 272

__global__ __launch_bounds__(1024, 4) void k_mega(
    const _Float16* __restrict__ pm_hi, const _Float16* __restrict__ pm_lo,
    const _Float16* __restrict__ Bhi, const _Float16* __restrict__ Blo,
    const _Float16* __restrict__ mBhi, const _Float16* __restrict__ mBlo,
    const float* __restrict__ sb, const float* __restrict__ vb,
    const float* __restrict__ sW0, const float* __restrict__ sb0,
    const float* __restrict__ r, const float* __restrict__ a,
    const _Float16* __restrict__ oBhi, const _Float16* __restrict__ oBlo,
    const float* __restrict__ wub, const float* __restrict__ wdb,
    const float* __restrict__ wfW,
    float* __restrict__ out)
{
    const int tid  = threadIdx.x;
    const int lane = tid & 63;
    const int wv   = tid >> 6;        // 0..15
    const int wg   = wv >> 2;         // walker pair group 0..3 (s-GEMM)
    const int wv4  = wv & 3;          // n-tile group (s-GEMM)
    const int m16  = lane & 15;
    const int quad = lane >> 4;
    const int b0   = blockIdx.x * 8;
    const int lw0  = wg * 2;          // local walkers lw0, lw0+1 (0..7)
    const int nb0  = wv4 * 64;

    __shared__ _Float16 sH[128][SROW];    // 67,584 B  [walker*16+e][k]
    __shared__ _Float16 sL[128][SROW];    // 67,584 B
    __shared__ _Float16 mH[16][MROW];     //  8,704 B  rows: mu w0..7, md w0..7
    __shared__ _Float16 mL[16][MROW];     //  8,704 B
    __shared__ float    ZshL[8][256];     //  8,192 B
    // total 160,768 B -> 1 block/CU, 16 waves

    // ========== prologue: fused k_s0 (embedding + first s layer, 8 walkers) ==
    {
        char*  sbase = (char*)&sH[0][0];
        float* pinA  = (float*)sbase;              // [8][16][16][4] 32,768 B (in sH)
        float* blkA  = (float*)(sbase + 32768);    // [8][16][56]    28,672 B (in sH)
        float* seA   = (float*)&ZshL[0][0];        // [8][16][16]     8,192 B (= ZshL)
        float* rlA   = (float*)&mH[0][0];          // [8][48] = 1,536 B
        float* alA   = rlA + 384;                  // [12]
        float* sm0A  = alA + 16;                   // [8][2][16] 1,024 B
        float* pm0A  = (float*)&mL[0][0];          // [8][16][2][4] 4,096 B

        if (tid < 384) rlA[tid] = r[(size_t)b0 * 48 + tid];
        if (tid >= 384 && tid < 396) alA[tid - 384] = a[tid - 384];
        __syncthreads();

#pragma unroll
        for (int it = 0; it < 2; ++it) {
            const int task = it * 1024 + tid;
            const int w = task >> 8, jj = (task >> 4) & 15, i = task & 15;
            const float* rw = rlA + w * 48;
            float dx = rw[jj * 3 + 0] - rw[i * 3 + 0];
            float dy = rw[jj * 3 + 1] - rw[i * 3 + 1];
            float dz = rw[jj * 3 + 2] - rw[i * 3 + 2];
            float ee = (i == jj) ? 1.0f : 0.0f;
            float len = sqrtf((dx + ee) * (dx + ee) + (dy + ee) * (dy + ee) + (dz + ee) * (dz + ee));
            float* p = pinA + (((w * 16 + jj) * 16 + i) << 2);
            p[0] = dx; p[1] = dy; p[2] = dz; p[3] = len;
        }
        if (tid < 128) {
            const int w = tid >> 4, e = tid & 15;
            const float* rw = rlA + w * 48;
#pragma unroll
            for (int at = 0; at < 4; ++at) {
                float dx = rw[e * 3 + 0] - alA[at * 3 + 0];
                float dy = rw[e * 3 + 1] - alA[at * 3 + 1];
                float dz = rw[e * 3 + 2] - alA[at * 3 + 2];
                float ln = sqrtf(dx * dx + dy * dy + dz * dz);
                float* p = seA + (w * 16 + e) * 16 + at * 4;
                p[0] = dx; p[1] = dy; p[2] = dz; p[3] = ln;
            }
        }
        __syncthreads();

        if (tid < 256) {
            const int w = tid >> 5, h = (tid >> 4) & 1, f = tid & 15;
            float s = 0.f;
            for (int e = 0; e < 8; ++e) s += seA[(w * 16 + h * 8 + e) * 16 + f];
            sm0A[(w * 2 + h) * 16 + f] = s * 0.125f;
        }
        {
            const int w = tid >> 7, jj = (tid >> 3) & 15, h = (tid >> 2) & 1, f = tid & 3;
            float s = 0.f;
            for (int i2 = 0; i2 < 8; ++i2)
                s += pinA[(((w * 16 + jj) * 16 + h * 8 + i2) << 2) + f];
            pm0A[((w * 16 + jj) * 2 + h) * 4 + f] = s * 0.125f;
        }
        __syncthreads();

        for (int t = tid; t < 8 * 16 * 56; t += 1024) {
            const int w = t / 896, rem = t % 896, e = rem / 56, k = rem % 56;
            float v;
            if (k < 16)      v = seA[(w * 16 + e) * 16 + k];
            else if (k < 32) v = sm0A[(w * 2 + 0) * 16 + (k - 16)];
            else if (k < 48) v = sm0A[(w * 2 + 1) * 16 + (k - 32)];
            else if (k < 52) v = pm0A[((w * 16 + e) * 2 + 0) * 4 + (k - 48)];
            else             v = pm0A[((w * 16 + e) * 2 + 1) * 4 + (k - 52)];
            blkA[(w * 16 + e) * 56 + k] = v;
        }
        __syncthreads();

        // GEMV (k_s0-identical per walker): thread = (col n0, walkers wsel/wsel+4)
        const int n0 = tid & 255, wsel = tid >> 8;   // 0..3
        float accA[16], accB[16];
#pragma unroll
        for (int e = 0; e < 16; ++e) { accA[e] = sb0[n0]; accB[e] = sb0[n0]; }
        for (int k = 0; k < 56; k += 4) {
            float w0 = sW0[(k + 0) * 256 + n0];
            float w1 = sW0[(k + 1) * 256 + n0];
            float w2 = sW0[(k + 2) * 256 + n0];
            float w3 = sW0[(k + 3) * 256 + n0];
#pragma unroll
            for (int e = 0; e < 16; ++e) {
                float4 sa = *(const float4*)&blkA[((wsel    ) * 16 + e) * 56 + k];
                float4 sc = *(const float4*)&blkA[((wsel + 4) * 16 + e) * 56 + k];
                accA[e] += sa.x * w0 + sa.y * w1 + sa.z * w2 + sa.w * w3;
                accB[e] += sc.x * w0 + sc.y * w1 + sc.z * w2 + sc.w * w3;
            }
        }
        __syncthreads();   // all blk/se reads complete before sH/sL overwrite

#pragma unroll
        for (int e = 0; e < 16; ++e) {
            _Float16 hi, lo;
            split16(fast_tanh(accA[e]), hi, lo);
            sH[wsel * 16 + e][n0] = hi;
            sL[wsel * 16 + e][n0] = lo;
            split16(fast_tanh(accB[e]), hi, lo);
            sH[(wsel + 4) * 16 + e][n0] = hi;
            sL[(wsel + 4) * 16 + e][n0] = lo;
        }
    }
    __syncthreads();

    // ========== means for layer 0 (reads rounded s) ==========
    {
        const int w  = tid >> 7;          // 0..7
        const int h  = (tid >> 6) & 1;
        const int k0 = (tid & 63) * 4;
        float s0 = 0.f, s1 = 0.f, s2 = 0.f, s3 = 0.f;
#pragma unroll
        for (int e = 0; e < 8; ++e) {
            const int row = w * 16 + h * 8 + e;
            f16x4 hv = *(const f16x4*)&sH[row][k0];
            f16x4 lv = *(const f16x4*)&sL[row][k0];
            s0 += (float)hv[0] + (float)lv[0];
            s1 += (float)hv[1] + (float)lv[1];
            s2 += (float)hv[2] + (float)lv[2];
            s3 += (float)hv[3] + (float)lv[3];
        }
        const int mrow = h * 8 + w;
        f16x4 hq, lq;
        _Float16 hi, lo;
        split16(s0 * 0.125f, hi, lo); hq[0] = hi; lq[0] = lo;
        split16(s1 * 0.125f, hi, lo); hq[1] = hi; lq[1] = lo;
        split16(s2 * 0.125f, hi, lo); hq[2] = hi; lq[2] = lo;
        split16(s3 * 0.125f, hi, lo); hq[3] = hi; lq[3] = lo;
        *(f16x4*)&mH[mrow][k0] = hq;
        *(f16x4*)&mL[mrow][k0] = lq;
    }

    // ========== init register-resident residual (rounded s, layer-0-exact) ==
    float resv[2][4][4];   // [mt][nt][reg]
#pragma unroll
    for (int mt = 0; mt < 2; ++mt)
#pragma unroll
        for (int nt = 0; nt < 4; ++nt) {
            const int n = nb0 + nt * 16 + m16;
#pragma unroll
            for (int reg = 0; reg < 4; ++reg) {
                const int row = (lw0 + mt) * 16 + quad * 4 + reg;
                resv[mt][nt][reg] = (float)sH[row][n] + (float)sL[row][n];
            }
        }
    __syncthreads();   // B1 (once)

    for (int l = 0; l < 5; ++l) {
        const float* bias = (l < 4) ? (sb + l * 256) : vb;
        const _Float16* pmH = pm_hi + (size_t)l * PM_STAGE;
        const _Float16* pmL = pm_lo + (size_t)l * PM_STAGE;
        const _Float16* Bh  = Bhi + (size_t)l * BPK_L;
        const _Float16* Bl  = Blo + (size_t)l * BPK_L;

        // ---- fused MFMA phase
        f32x4 acc[2][4];
        f32x4 macc0 = (f32x4){0.f, 0.f, 0.f, 0.f};   // mu chain
        f32x4 macc1 = (f32x4){0.f, 0.f, 0.f, 0.f};   // md chain
#pragma unroll
        for (int mt = 0; mt < 2; ++mt)
#pragma unroll
            for (int nt = 0; nt < 4; ++nt) acc[mt][nt] = (f32x4){0.f, 0.f, 0.f, 0.f};

        // -- PREFETCH pm A-frags (L3 latency hides under the MFMA loop)
        f16x8 pAh[2][2], pAl[2][2];   // [h][mt]
        {
            int aP[2];
#pragma unroll
            for (int mt = 0; mt < 2; ++mt)
                aP[mt] = ((b0 + lw0 + mt) * 16 + m16) * 64 + quad * 8;
#pragma unroll
            for (int h = 0; h < 2; ++h)
#pragma unroll
                for (int mt = 0; mt < 2; ++mt) {
                    pAh[h][mt] = *(const f16x8*)(pmH + aP[mt] + h * 32);
                    pAl[h][mt] = *(const f16x8*)(pmL + aP[mt] + h * 32);
                }
        }

        const _Float16* Bhw = Bh + (size_t)(wv4 * 4) * 512 + (size_t)lane * 8;
        const _Float16* Blw = Bl + (size_t)(wv4 * 4) * 512 + (size_t)lane * 8;
        const _Float16* mBh = mBhi + (size_t)l * MBK_L + (size_t)wv * 512 + (size_t)lane * 8;
        const _Float16* mBl = mBlo + (size_t)l * MBK_L + (size_t)wv * 512 + (size_t)lane * 8;
        const f16x8 z16 = (f16x8){0, 0, 0, 0, 0, 0, 0, 0};

#pragma unroll
        for (int kc = 0; kc < 8; ++kc) {
            // -- mean-GEMM sub-steps: wave owns ONE n-tile (n = wv*16+m16);
            //    independent mu (hh=0) and md (hh=1) accumulator chains
#pragma unroll
            for (int hh = 0; hh < 2; ++hh) {
                const int kk0  = kc * 32 + quad * 8;
                const int mrow = hh * 8 + (m16 & 7);
                f16x8 mah = *(const f16x8*)&mH[mrow][kk0];
                f16x8 mal = *(const f16x8*)&mL[mrow][kk0];
                if (m16 >= 8) { mah = z16; mal = z16; }
                const size_t mo = (size_t)(hh * 8 + kc) * 8192;
                f16x8 bh = *(const f16x8*)(mBh + mo);
                f16x8 bl = *(const f16x8*)(mBl + mo);
                if (hh == 0) {
                    macc0 = __builtin_amdgcn_mfma_f32_16x16x32_f16(mah, bh, macc0, 0, 0, 0);
                    macc0 = __builtin_amdgcn_mfma_f32_16x16x32_f16(mah, bl, macc0, 0, 0, 0);
                    macc0 = __builtin_amdgcn_mfma_f32_16x16x32_f16(mal, bh, macc0, 0, 0, 0);
                } else {
                    macc1 = __builtin_amdgcn_mfma_f32_16x16x32_f16(mah, bh, macc1, 0, 0, 0);
                    macc1 = __builtin_amdgcn_mfma_f32_16x16x32_f16(mah, bl, macc1, 0, 0, 0);
                    macc1 = __builtin_amdgcn_mfma_f32_16x16x32_f16(mal, bh, macc1, 0, 0, 0);
                }
            }
            // -- s-part step kc
            f16x8 ah[2], al[2];
#pragma unroll
            for (int mt = 0; mt < 2; ++mt) {
                const int row = (lw0 + mt) * 16 + m16;
                ah[mt] = *(const f16x8*)&sH[row][kc * 32 + quad * 8];
                al[mt] = *(const f16x8*)&sL[row][kc * 32 + quad * 8];
            }
#pragma unroll
            for (int nt = 0; nt < 4; ++nt) {
                f16x8 bh = *(const f16x8*)(Bhw + (size_t)kc * 8192 + nt * 512);
                f16x8 bl = *(const f16x8*)(Blw + (size_t)kc * 8192 + nt * 512);
#pragma unroll
                for (int mt = 0; mt < 2; ++mt) {
                    acc[mt][nt] = __builtin_amdgcn_mfma_f32_16x16x32_f16(ah[mt], bh, acc[mt][nt], 0, 0, 0);
                    acc[mt][nt] = __builtin_amdgcn_mfma_f32_16x16x32_f16(ah[mt], bl, acc[mt][nt], 0, 0, 0);
                    acc[mt][nt] = __builtin_amdgcn_mfma_f32_16x16x32_f16(al[mt], bh, acc[mt][nt], 0, 0, 0);
                }
            }
        }
        // -- p-part: kc 8..9 (pu, pd) from the prefetched registers
#pragma unroll
        for (int h = 0; h < 2; ++h) {
#pragma unroll
            for (int nt = 0; nt < 4; ++nt) {
                f16x8 bh = *(const f16x8*)(Bhw + (size_t)(8 + h) * 8192 + nt * 512);
                f16x8 bl = *(const f16x8*)(Blw + (size_t)(8 + h) * 8192 + nt * 512);
#pragma unroll
                for (int mt = 0; mt < 2; ++mt) {
                    acc[mt][nt] = __builtin_amdgcn_mfma_f32_16x16x32_f16(pAh[h][mt], bh, acc[mt][nt], 0, 0, 0);
                    acc[mt][nt] = __builtin_amdgcn_mfma_f32_16x16x32_f16(pAh[h][mt], bl, acc[mt][nt], 0, 0, 0);
                    acc[mt][nt] = __builtin_amdgcn_mfma_f32_16x16x32_f16(pAl[h][mt], bh, acc[mt][nt], 0, 0, 0);
                }
            }
        }
        // -- Z write: D rows 0..7 (quad 0,1) = walkers 0..7
        if (quad < 2) {
            const int n = wv * 16 + m16;
            const float bv = bias[n];
#pragma unroll
            for (int reg = 0; reg < 4; ++reg)
                ZshL[quad * 4 + reg][n] = bv + (macc0[reg] + macc1[reg]);
        }
        __syncthreads();   // B2: ZshL ready, all sH/sL/mH/mL reads complete

        // ---- epilogue (tanh + register residual) with FUSED next-layer means
#pragma unroll
        for (int mt = 0; mt < 2; ++mt) {
#pragma unroll
            for (int nt = 0; nt < 4; ++nt) {
                const int n  = nb0 + nt * 16 + m16;
                const float zv = ZshL[lw0 + mt][n];
                float sum4 = 0.f;
#pragma unroll
                for (int reg = 0; reg < 4; ++reg) {
                    const int row = (lw0 + mt) * 16 + quad * 4 + reg;
                    float t = fast_tanh(acc[mt][nt][reg] + zv);
                    if (l != 4) t += resv[mt][nt][reg];
                    resv[mt][nt][reg] = t;
                    sum4 += t;
                    _Float16 hi, lo; split16(t, hi, lo);
                    sH[row][n] = hi;
                    sL[row][n] = lo;
                }
                if (l != 4) {
                    float sum8 = sum4 + __shfl_xor(sum4, 16);
                    if ((quad & 1) == 0) {
                        const int mrow = (quad >> 1) * 8 + (lw0 + mt);
                        _Float16 hi, lo; split16(sum8 * 0.125f, hi, lo);
                        mH[mrow][n] = hi;
                        mL[mrow][n] = lo;
                    }
                }
            }
        }
        __syncthreads();   // B3: new s + means visible to next phase
    }

    // ======================= fused orbitals + slogdet =======================
    const int pg    = wv >> 2;        // walker pair 0..3
    const int ospin = (wv >> 1) & 1;
    const int nhalf = wv & 1;

    // envl -> aliased onto mH (means dead after layer-4 gemm)
    float* envp = (float*)&mH[0][0];      // [8][16]
    if (tid < 128) {
        const int w = tid >> 4, e = tid & 15;
        float ex = 0.f;
#pragma unroll
        for (int at = 0; at < 4; ++at) {
            float dx = r[(b0 + w) * 48 + e * 3 + 0] - a[at * 3 + 0];
            float dy = r[(b0 + w) * 48 + e * 3 + 1] - a[at * 3 + 1];
            float dz = r[(b0 + w) * 48 + e * 3 + 2] - a[at * 3 + 2];
            ex += __expf(-sqrtf(dx * dx + dy * dy + dz * dz));
        }
        envp[w * 16 + e] = ex;
    }

    // orbital GEMM: A rows from LDS s
    const int arow = (pg * 2 + (m16 >> 3)) * 16 + ospin * 8 + (m16 & 7);
    f32x4 oacc[4];
#pragma unroll
    for (int nt = 0; nt < 4; ++nt) oacc[nt] = (f32x4){0.f, 0.f, 0.f, 0.f};

#pragma unroll
    for (int kc = 0; kc < 8; ++kc) {
        f16x8 ah = *(const f16x8*)&sH[arow][kc * 32 + quad * 8];
        f16x8 al = *(const f16x8*)&sL[arow][kc * 32 + quad * 8];
#pragma unroll
        for (int nt = 0; nt < 4; ++nt) {
            const size_t bo = (((size_t)ospin * 8 + kc) * 8 + nhalf * 4 + nt) * 512 + (size_t)lane * 8;
            f16x8 bh = *(const f16x8*)(oBhi + bo);
            f16x8 bl = *(const f16x8*)(oBlo + bo);
            oacc[nt] = __builtin_amdgcn_mfma_f32_16x16x32_f16(ah, bh, oacc[nt], 0, 0, 0);
            oacc[nt] = __builtin_amdgcn_mfma_f32_16x16x32_f16(ah, bl, oacc[nt], 0, 0, 0);
            oacc[nt] = __builtin_amdgcn_mfma_f32_16x16x32_f16(al, bh, oacc[nt], 0, 0, 0);
            oacc[nt] = __builtin_amdgcn_mfma_f32_16x16x32_f16(al, bl, oacc[nt], 0, 0, 0);
        }
    }
    __syncthreads();   // all sH/sL A-reads + envl writes complete

    // scatter -> orbL aliased onto sH ([8][2][16][66] f32 = 67,584 B = exact fit)
    float* orbp = (float*)&sH[0][0];
    const float* bm = ospin ? wdb : wub;
#pragma unroll
    for (int nt = 0; nt < 4; ++nt) {
        const int c = nhalf * 64 + nt * 16 + m16;
        const float bv = bm[c];
        const int d = c & 15;
        const int jrow = c >> 4;
#pragma unroll
        for (int reg = 0; reg < 4; ++reg) {
            const int m = quad * 4 + reg;
            const int wl = pg * 2 + (m >> 3);
            const int el = m & 7;
            orbp[((wl * 2 + ospin) * 16 + d) * 66 + jrow * 8 + el] =
                (oacc[nt][reg] + bv) * envp[wl * 16 + ospin * 8 + el];
        }
    }
    __syncthreads();

    // determinants + lse: threads 0..127 = (walker w = tid>>4, det d = tid&15)
    if (tid < 128) {
        const int w = tid >> 4, d = tid & 15;
        float M[8][8];
#pragma unroll
        for (int rr = 0; rr < 8; ++rr)
#pragma unroll
            for (int cc = 0; cc < 8; ++cc)
                M[rr][cc] = orbp[((w * 2 + 0) * 16 + d) * 66 + rr * 8 + cc];
        float s1, l1; slogdet8(M, s1, l1);
#pragma unroll
        for (int rr = 0; rr < 8; ++rr)
#pragma unroll
            for (int cc = 0; cc < 8; ++cc)
                M[rr][cc] = orbp[((w * 2 + 1) * 16 + d) * 66 + rr * 8 + cc];
        float s2, l2; slogdet8(M, s2, l2);
        float sgn = s1 * s2;
        float ld  = l1 + l2;

        float m = ld;
        m = fmaxf(m, __shfl_xor(m, 1));
        m = fmaxf(m, __shfl_xor(m, 2));
        m = fmaxf(m, __shfl_xor(m, 4));
        m = fmaxf(m, __shfl_xor(m, 8));
        float sub = sgn * __expf(ld - m) * wfW[d];
        sub += __shfl_xor(sub, 1);
        sub += __shfl_xor(sub, 2);
        sub += __shfl_xor(sub, 4);
        sub += __shfl_xor(sub, 8);
        if (d == 0) out[b0 + w] = logf(fabsf(sub)) + m;
    }
}

// ---------------------------------------------------------------------------
extern "C" void kernel_launch(void* const* d_in, const int* in_sizes, int n_in,
                              void* d_out, int out_size, void* d_ws, size_t ws_size,
                              hipStream_t stream) {
    (void)in_sizes; (void)n_in; (void)out_size; (void)ws_size;
    const float* r   = (const float*)d_in[0];
    const float* a   = (const float*)d_in[1];
    const float* sW0 = (const float*)d_in[2];
    const float* sb0 = (const float*)d_in[3];
    const float* sW  = (const float*)d_in[4];
    const float* sb  = (const float*)d_in[5];
    const float* pW0 = (const float*)d_in[6];
    const float* pb0 = (const float*)d_in[7];
    const float* pW  = (const float*)d_in[8];
    const float* pb  = (const float*)d_in[9];
    const float* vW  = (const float*)d_in[10];
    const float* vb  = (const float*)d_in[11];
    const float* wuW = (const float*)d_in[12];
    const float* wub = (const float*)d_in[13];
    const float* wdW = (const float*)d_in[14];
    const float* wdb = (const float*)d_in[15];
    const float* wfW = (const float*)d_in[16];
    float* out = (float*)d_out;

    // workspace layout (bytes)
    char* wsb = (char*)d_ws;
    _Float16* pm_hi = (_Float16*)(wsb + 0);          // 20,971,520 (5 stages)
    _Float16* pm_lo = (_Float16*)(wsb + 20971520);   // 20,971,520
    _Float16* Bhi   = (_Float16*)(wsb + 41943040);   //    819,200
    _Float16* Blo   = (_Float16*)(wsb + 42762240);   //    819,200
    _Float16* pBhi  = (_Float16*)(wsb + 43581440);   //      8,192
    _Float16* pBlo  = (_Float16*)(wsb + 43589632);   //      8,192
    _Float16* oBhi  = (_Float16*)(wsb + 43597824);   //    131,072
    _Float16* oBlo  = (_Float16*)(wsb + 43728896);   //    131,072
    _Float16* mBhi  = (_Float16*)(wsb + 43859968);   //  1,310,720 (5 layers)
    _Float16* mBlo  = (_Float16*)(wsb + 45170688);   //  1,310,720
    // total 46,481,408 (< 79,691,776 known-safe)

    k_prep_all<<<150, 256, 0, stream>>>(sW, vW, pW, wuW, wdW,
                                        Bhi, Blo, pBhi, pBlo, oBhi, oBlo,
                                        mBhi, mBlo);
    k_pstream<<<NB * 4, 256, 0, stream>>>(r, pW0, pb0, pb, pBhi, pBlo, pm_hi, pm_lo);
    k_mega<<<NB / 8, 1024, 0, stream>>>(pm_hi, pm_lo, Bhi, Blo, mBhi, mBlo,
                                        sb, vb, sW0, sb0,
                                        r, a, oBhi, oBlo, wub, wdb, wfW, out);
}

// Round 13
// 327.518 us; speedup vs baseline: 1.0812x; 1.0812x over previous
//
#include <hip/hip_runtime.h>
#include <math.h>

#define NB 2048
#define PM_STAGE 2097152   // elements per pmeans stage (2048*16*2*32)
#define BPK_L    81920     // elements per packed weight layer (10*16*64*8)
#define MBK_L    131072    // elements per packed mean-W layer (16*16*64*8)

typedef float    f32x4 __attribute__((ext_vector_type(4)));
typedef _Float16 f16x8 __attribute__((ext_vector_type(8)));
typedef _Float16 f16x4 __attribute__((ext_vector_type(4)));

__device__ __forceinline__ float fast_tanh(float x) {
    float ax = fabsf(x);
    float e  = __expf(2.0f * ax);
    float t  = 1.0f - 2.0f / (e + 1.0f);
    return copysignf(t, x);
}

__device__ __forceinline__ void split16(float x, _Float16& hi, _Float16& lo) {
    hi = (_Float16)x;
    lo = (_Float16)(x - (float)hi);
}

// ---------------------------------------------------------------------------
// MERGED one-time weight packs (single dispatch). (R11-verbatim, verified)
// ---------------------------------------------------------------------------
__global__ __launch_bounds__(256) void k_prep_all(
    const float* __restrict__ sW, const float* __restrict__ vW,
    const float* __restrict__ pW,
    const float* __restrict__ wuW, const float* __restrict__ wdW,
    _Float16* __restrict__ Bhi, _Float16* __restrict__ Blo,
    _Float16* __restrict__ pBhi, _Float16* __restrict__ pBlo,
    _Float16* __restrict__ oBhi, _Float16* __restrict__ oBlo,
    _Float16* __restrict__ mBhi, _Float16* __restrict__ mBlo)
{
    const int blk  = blockIdx.x;
    const int lane = threadIdx.x & 63;
    const int sub  = threadIdx.x >> 6;

    if (blk < 50) {
        const int l  = blk / 10;
        const int kc = blk % 10;
        const float* Wsrc = (l < 4) ? (sW + (size_t)l * 212992) : vW;
        const size_t base = (size_t)l * BPK_L + (size_t)kc * 8192;
#pragma unroll
        for (int ntl = 0; ntl < 4; ++ntl) {
            const int nt = sub * 4 + ntl;
            const int n  = nt * 16 + (lane & 15);
#pragma unroll
            for (int j = 0; j < 8; ++j) {
                const int f = kc * 32 + (lane >> 4) * 8 + j;   // 0..319
                int row;
                if (f < 256)      row = f;
                else if (f < 288) row = 768 + (f - 256);
                else              row = 800 + (f - 288);
                const float w = Wsrc[row * 256 + n];
                _Float16 hi, lo; split16(w, hi, lo);
                Bhi[base + (size_t)(nt * 64 + lane) * 8 + j] = hi;
                Blo[base + (size_t)(nt * 64 + lane) * 8 + j] = lo;
            }
        }
    } else if (blk < 54) {
        if (threadIdx.x < 128) {
            const int l   = blk - 50;
            const int nt  = threadIdx.x >> 6;
            const int m16 = lane & 15, quad = lane >> 4;
#pragma unroll
            for (int j = 0; j < 8; ++j) {
                float w = pW[l * 1024 + (quad * 8 + j) * 32 + nt * 16 + m16];
                _Float16 hi, lo; split16(w, hi, lo);
                pBhi[((size_t)l * 2 + nt) * 512 + lane * 8 + j] = hi;
                pBlo[((size_t)l * 2 + nt) * 512 + lane * 8 + j] = lo;
            }
        }
    } else if (blk < 70) {
        const int ob   = blk - 54;       // spin*8 + kc
        const int spin = ob >> 3, kc = ob & 7;
        const float* W = spin ? wdW : wuW;
#pragma unroll
        for (int t = 0; t < 2; ++t) {
            const int nt = sub * 2 + t;
            const int n  = nt * 16 + (lane & 15);
#pragma unroll
            for (int j = 0; j < 8; ++j) {
                const int k = kc * 32 + (lane >> 4) * 8 + j;
                float w = W[k * 128 + n];
                _Float16 hi, lo; split16(w, hi, lo);
                const size_t o = (((size_t)spin * 8 + kc) * 8 + nt) * 512 + (size_t)lane * 8 + j;
                oBhi[o] = hi; oBlo[o] = lo;
            }
        }
    } else {
        const int mb = blk - 70;         // l*16 + kk
        const int l  = mb >> 4;
        const int kk = mb & 15;          // hh*8 + kc
        const float* Wsrc = (l < 4) ? (sW + (size_t)l * 212992) : vW;
        const size_t base = (size_t)l * MBK_L + (size_t)kk * 8192;
#pragma unroll
        for (int ntl = 0; ntl < 4; ++ntl) {
            const int nt = sub * 4 + ntl;
            const int n  = nt * 16 + (lane & 15);
#pragma unroll
            for (int j = 0; j < 8; ++j) {
                const int row = 256 + kk * 32 + (lane >> 4) * 8 + j;
                const float w = Wsrc[row * 256 + n];
                _Float16 hi, lo; split16(w, hi, lo);
                mBhi[base + (size_t)(nt * 64 + lane) * 8 + j] = hi;
                mBlo[base + (size_t)(nt * 64 + lane) * 8 + j] = lo;
            }
        }
    }
}

// ---------------------------------------------------------------------------
// p-stream via split-f16 MFMA (3-term), barrier-free (R1-verbatim, verified).
// ---------------------------------------------------------------------------
__global__ __launch_bounds__(256) void k_pstream(
    const float* __restrict__ r,
    const float* __restrict__ pW0, const float* __restrict__ pb0,
    const float* __restrict__ pb,
    const _Float16* __restrict__ pBhi, const _Float16* __restrict__ pBlo,
    _Float16* __restrict__ pm_hi, _Float16* __restrict__ pm_lo)
{
    const int b    = blockIdx.x >> 2;
    const int jg   = blockIdx.x & 3;
    const int tid  = threadIdx.x;
    const int lane = tid & 63;
    const int wvl  = tid >> 6;           // 0..3
    const int j    = jg * 4 + wvl;       // this wave's j column (0..15)
    const int m16  = lane & 15;
    const int quad = lane >> 4;

    __shared__ float rl[48];
    __shared__ float pst[4][32][17];     // wave-private slices, stride 17 (odd)

    if (tid < 48) rl[tid] = r[b * 48 + tid];
    __syncthreads();                     // only barrier in the kernel

    const float rjx = rl[j * 3 + 0];
    const float rjy = rl[j * 3 + 1];
    const float rjz = rl[j * 3 + 2];

    const int f0 = m16, f1 = m16 + 16;
    float pcur[2][4];   // [nt][reg], D-layout residual state (rows i = quad*4+reg)

    // ---- layer 0
#pragma unroll
    for (int reg = 0; reg < 4; ++reg) {
        const int i = quad * 4 + reg;
        float dx = rjx - rl[i * 3 + 0];
        float dy = rjy - rl[i * 3 + 1];
        float dz = rjz - rl[i * 3 + 2];
        float ee = (i == j) ? 1.0f : 0.0f;
        float len = sqrtf((dx + ee) * (dx + ee) + (dy + ee) * (dy + ee) + (dz + ee) * (dz + ee));
#pragma unroll
        for (int nt = 0; nt < 2; ++nt) {
            const int k = nt ? f1 : f0;
            float acc = pb0[k] + dx * pW0[k] + dy * pW0[32 + k]
                      + dz * pW0[64 + k] + len * pW0[96 + k];
            float v = fast_tanh(acc);
            pcur[nt][reg] = v;
            pst[wvl][k][i] = v;
        }
    }
    asm volatile("s_waitcnt lgkmcnt(0)" ::: "memory");

    // ---- stage-0 means
    {
        const int mh = lane >> 5, mk = lane & 31;
        float s = 0.f;
#pragma unroll
        for (int i8 = 0; i8 < 8; ++i8) s += pst[wvl][mk][mh * 8 + i8];
        _Float16 hi, lo; split16(s * 0.125f, hi, lo);
        const size_t o = (size_t)b * 1024 + j * 64 + lane;
        pm_hi[o] = hi;
        pm_lo[o] = lo;
    }

    for (int l = 0; l < 4; ++l) {
        f16x8 ah, al;
#pragma unroll
        for (int jj = 0; jj < 8; ++jj) {
            float v = pst[wvl][quad * 8 + jj][m16];
            _Float16 hi, lo; split16(v, hi, lo);
            ah[jj] = hi; al[jj] = lo;
        }
        const _Float16* bhp = pBhi + ((size_t)l * 2) * 512 + (size_t)lane * 8;
        const _Float16* blp = pBlo + ((size_t)l * 2) * 512 + (size_t)lane * 8;
        f32x4 acc0 = (f32x4){0.f, 0.f, 0.f, 0.f};
        f32x4 acc1 = (f32x4){0.f, 0.f, 0.f, 0.f};
        {
            f16x8 bh = *(const f16x8*)(bhp);
            f16x8 bl = *(const f16x8*)(blp);
            acc0 = __builtin_amdgcn_mfma_f32_16x16x32_f16(ah, bh, acc0, 0, 0, 0);
            acc0 = __builtin_amdgcn_mfma_f32_16x16x32_f16(ah, bl, acc0, 0, 0, 0);
            acc0 = __builtin_amdgcn_mfma_f32_16x16x32_f16(al, bh, acc0, 0, 0, 0);
            bh = *(const f16x8*)(bhp + 512);
            bl = *(const f16x8*)(blp + 512);
            acc1 = __builtin_amdgcn_mfma_f32_16x16x32_f16(ah, bh, acc1, 0, 0, 0);
            acc1 = __builtin_amdgcn_mfma_f32_16x16x32_f16(ah, bl, acc1, 0, 0, 0);
            acc1 = __builtin_amdgcn_mfma_f32_16x16x32_f16(al, bh, acc1, 0, 0, 0);
        }
        const float b0v = pb[l * 32 + f0];
        const float b1v = pb[l * 32 + f1];
        asm volatile("" ::: "memory");
#pragma unroll
        for (int reg = 0; reg < 4; ++reg) {
            const int i = quad * 4 + reg;
            pcur[0][reg] += fast_tanh(acc0[reg] + b0v);
            pcur[1][reg] += fast_tanh(acc1[reg] + b1v);
            pst[wvl][f0][i] = pcur[0][reg];
            pst[wvl][f1][i] = pcur[1][reg];
        }
        asm volatile("s_waitcnt lgkmcnt(0)" ::: "memory");
        {
            const int mh = lane >> 5, mk = lane & 31;
            float s = 0.f;
#pragma unroll
            for (int i8 = 0; i8 < 8; ++i8) s += pst[wvl][mk][mh * 8 + i8];
            _Float16 hi, lo; split16(s * 0.125f, hi, lo);
            const size_t o = (size_t)(l + 1) * PM_STAGE + (size_t)b * 1024 + j * 64 + lane;
            pm_hi[o] = hi;
            pm_lo[o] = lo;
        }
    }
}

// ---------------------------------------------------------------------------
__device__ __forceinline__ void slogdet8(float M[8][8], float& sgn_out, float& ld_out) {
    float sgn = 1.f, ld = 0.f;
#pragma unroll
    for (int k = 0; k < 8; ++k) {
        float best = fabsf(M[k][k]);
        int p = k;
#pragma unroll
        for (int rr = k + 1; rr < 8; ++rr) {
            float v = fabsf(M[rr][k]);
            if (v > best) { best = v; p = rr; }
        }
        if (p != k) sgn = -sgn;
#pragma unroll
        for (int rr = k + 1; rr < 8; ++rr) {
            bool sw = (rr == p);
#pragma unroll
            for (int cc = k; cc < 8; ++cc) {
                float x = M[k][cc], y = M[rr][cc];
                M[k][cc]  = sw ? y : x;
                M[rr][cc] = sw ? x : y;
            }
        }
        float piv = M[k][k];
        if (piv < 0.f) sgn = -sgn;
        ld += logf(fabsf(piv));
        float inv = 1.f / piv;
#pragma unroll
        for (int rr = k + 1; rr < 8; ++rr) {
            float f = M[rr][k] * inv;
#pragma unroll
            for (int cc = k + 1; cc < 8; ++cc) M[rr][cc] -= f * M[k][cc];
        }
    }
    sgn_out = sgn; ld_out = ld;
}

// ---------------------------------------------------------------------------
// MEGA v12: R11-verbatim structure (REVERT of R12's register-residual — it
// spilled: unified VGPR/AGPR file was already at the 128/thread budget;
// WRITE_SIZE 9KB->91MB was scratch traffic). Only retained change vs R11:
// mean-GEMM accumulator split into mu/md chains (+4 regs, halves the 48-deep
// serial MFMA dependency; summed at Z write, fp32-order change ~1e-7).
// ---------------------------------------------------------------------------
#define SROW 264
#define MROW 272

__global__ __launch_bounds__(1024, 4) void k_mega(
    const _Float16* __restrict__ pm_hi, const _Float16* __restrict__ pm_lo,
    const _Float16* __restrict__ Bhi, const _Float16* __restrict__ Blo,
    const _Float16* __restrict__ mBhi, const _Float16* __restrict__ mBlo,
    const float* __restrict__ sb, const float* __restrict__ vb,
    const float* __restrict__ sW0, const float* __restrict__ sb0,
    const float* __restrict__ r, const float* __restrict__ a,
    const _Float16* __restrict__ oBhi, const _Float16* __restrict__ oBlo,
    const float* __restrict__ wub, const float* __restrict__ wdb,
    const float* __restrict__ wfW,
    float* __restrict__ out)
{
    const int tid  = threadIdx.x;
    const int lane = tid & 63;
    const int wv   = tid >> 6;        // 0..15
    const int wg   = wv >> 2;         // walker pair group 0..3 (s-GEMM)
    const int wv4  = wv & 3;          // n-tile group (s-GEMM)
    const int m16  = lane & 15;
    const int quad = lane >> 4;
    const int b0   = blockIdx.x * 8;
    const int lw0  = wg * 2;          // local walkers lw0, lw0+1 (0..7)
    const int nb0  = wv4 * 64;

    __shared__ _Float16 sH[128][SROW];    // 67,584 B  [walker*16+e][k]
    __shared__ _Float16 sL[128][SROW];    // 67,584 B
    __shared__ _Float16 mH[16][MROW];     //  8,704 B  rows: mu w0..7, md w0..7
    __shared__ _Float16 mL[16][MROW];     //  8,704 B
    __shared__ float    ZshL[8][256];     //  8,192 B
    // total 160,768 B -> 1 block/CU, 16 waves

    // ========== prologue: fused k_s0 (embedding + first s layer, 8 walkers) ==
    {
        char*  sbase = (char*)&sH[0][0];
        float* pinA  = (float*)sbase;              // [8][16][16][4] 32,768 B (in sH)
        float* blkA  = (float*)(sbase + 32768);    // [8][16][56]    28,672 B (in sH)
        float* seA   = (float*)&ZshL[0][0];        // [8][16][16]     8,192 B (= ZshL)
        float* rlA   = (float*)&mH[0][0];          // [8][48] = 1,536 B
        float* alA   = rlA + 384;                  // [12]
        float* sm0A  = alA + 16;                   // [8][2][16] 1,024 B
        float* pm0A  = (float*)&mL[0][0];          // [8][16][2][4] 4,096 B

        if (tid < 384) rlA[tid] = r[(size_t)b0 * 48 + tid];
        if (tid >= 384 && tid < 396) alA[tid - 384] = a[tid - 384];
        __syncthreads();

#pragma unroll
        for (int it = 0; it < 2; ++it) {
            const int task = it * 1024 + tid;
            const int w = task >> 8, jj = (task >> 4) & 15, i = task & 15;
            const float* rw = rlA + w * 48;
            float dx = rw[jj * 3 + 0] - rw[i * 3 + 0];
            float dy = rw[jj * 3 + 1] - rw[i * 3 + 1];
            float dz = rw[jj * 3 + 2] - rw[i * 3 + 2];
            float ee = (i == jj) ? 1.0f : 0.0f;
            float len = sqrtf((dx + ee) * (dx + ee) + (dy + ee) * (dy + ee) + (dz + ee) * (dz + ee));
            float* p = pinA + (((w * 16 + jj) * 16 + i) << 2);
            p[0] = dx; p[1] = dy; p[2] = dz; p[3] = len;
        }
        if (tid < 128) {
            const int w = tid >> 4, e = tid & 15;
            const float* rw = rlA + w * 48;
#pragma unroll
            for (int at = 0; at < 4; ++at) {
                float dx = rw[e * 3 + 0] - alA[at * 3 + 0];
                float dy = rw[e * 3 + 1] - alA[at * 3 + 1];
                float dz = rw[e * 3 + 2] - alA[at * 3 + 2];
                float ln = sqrtf(dx * dx + dy * dy + dz * dz);
                float* p = seA + (w * 16 + e) * 16 + at * 4;
                p[0] = dx; p[1] = dy; p[2] = dz; p[3] = ln;
            }
        }
        __syncthreads();

        if (tid < 256) {
            const int w = tid >> 5, h = (tid >> 4) & 1, f = tid & 15;
            float s = 0.f;
            for (int e = 0; e < 8; ++e) s += seA[(w * 16 + h * 8 + e) * 16 + f];
            sm0A[(w * 2 + h) * 16 + f] = s * 0.125f;
        }
        {
            const int w = tid >> 7, jj = (tid >> 3) & 15, h = (tid >> 2) & 1, f = tid & 3;
            float s = 0.f;
            for (int i2 = 0; i2 < 8; ++i2)
                s += pinA[(((w * 16 + jj) * 16 + h * 8 + i2) << 2) + f];
            pm0A[((w * 16 + jj) * 2 + h) * 4 + f] = s * 0.125f;
        }
        __syncthreads();

        for (int t = tid; t < 8 * 16 * 56; t += 1024) {
            const int w = t / 896, rem = t % 896, e = rem / 56, k = rem % 56;
            float v;
            if (k < 16)      v = seA[(w * 16 + e) * 16 + k];
            else if (k < 32) v = sm0A[(w * 2 + 0) * 16 + (k - 16)];
            else if (k < 48) v = sm0A[(w * 2 + 1) * 16 + (k - 32)];
            else if (k < 52) v = pm0A[((w * 16 + e) * 2 + 0) * 4 + (k - 48)];
            else             v = pm0A[((w * 16 + e) * 2 + 1) * 4 + (k - 52)];
            blkA[(w * 16 + e) * 56 + k] = v;
        }
        __syncthreads();

        // GEMV (k_s0-identical per walker): thread = (col n0, walkers wsel/wsel+4)
        const int n0 = tid & 255, wsel = tid >> 8;   // 0..3
        float accA[16], accB[16];
#pragma unroll
        for (int e = 0; e < 16; ++e) { accA[e] = sb0[n0]; accB[e] = sb0[n0]; }
        for (int k = 0; k < 56; k += 4) {
            float w0 = sW0[(k + 0) * 256 + n0];
            float w1 = sW0[(k + 1) * 256 + n0];
            float w2 = sW0[(k + 2) * 256 + n0];
            float w3 = sW0[(k + 3) * 256 + n0];
#pragma unroll
            for (int e = 0; e < 16; ++e) {
                float4 sa = *(const float4*)&blkA[((wsel    ) * 16 + e) * 56 + k];
                float4 sc = *(const float4*)&blkA[((wsel + 4) * 16 + e) * 56 + k];
                accA[e] += sa.x * w0 + sa.y * w1 + sa.z * w2 + sa.w * w3;
                accB[e] += sc.x * w0 + sc.y * w1 + sc.z * w2 + sc.w * w3;
            }
        }
        __syncthreads();   // all blk/se reads complete before sH/sL overwrite

#pragma unroll
        for (int e = 0; e < 16; ++e) {
            _Float16 hi, lo;
            split16(fast_tanh(accA[e]), hi, lo);
            sH[wsel * 16 + e][n0] = hi;
            sL[wsel * 16 + e][n0] = lo;
            split16(fast_tanh(accB[e]), hi, lo);
            sH[(wsel + 4) * 16 + e][n0] = hi;
            sL[(wsel + 4) * 16 + e][n0] = lo;
        }
    }
    __syncthreads();

    // ========== means for layer 0 (reads rounded s) ==========
    {
        const int w  = tid >> 7;          // 0..7
        const int h  = (tid >> 6) & 1;
        const int k0 = (tid & 63) * 4;
        float s0 = 0.f, s1 = 0.f, s2 = 0.f, s3 = 0.f;
#pragma unroll
        for (int e = 0; e < 8; ++e) {
            const int row = w * 16 + h * 8 + e;
            f16x4 hv = *(const f16x4*)&sH[row][k0];
            f16x4 lv = *(const f16x4*)&sL[row][k0];
            s0 += (float)hv[0] + (float)lv[0];
            s1 += (float)hv[1] + (float)lv[1];
            s2 += (float)hv[2] + (float)lv[2];
            s3 += (float)hv[3] + (float)lv[3];
        }
        const int mrow = h * 8 + w;
        f16x4 hq, lq;
        _Float16 hi, lo;
        split16(s0 * 0.125f, hi, lo); hq[0] = hi; lq[0] = lo;
        split16(s1 * 0.125f, hi, lo); hq[1] = hi; lq[1] = lo;
        split16(s2 * 0.125f, hi, lo); hq[2] = hi; lq[2] = lo;
        split16(s3 * 0.125f, hi, lo); hq[3] = hi; lq[3] = lo;
        *(f16x4*)&mH[mrow][k0] = hq;
        *(f16x4*)&mL[mrow][k0] = lq;
    }
    __syncthreads();   // B1 (once)

    for (int l = 0; l < 5; ++l) {
        const float* bias = (l < 4) ? (sb + l * 256) : vb;
        const _Float16* pmH = pm_hi + (size_t)l * PM_STAGE;
        const _Float16* pmL = pm_lo + (size_t)l * PM_STAGE;
        const _Float16* Bh  = Bhi + (size_t)l * BPK_L;
        const _Float16* Bl  = Blo + (size_t)l * BPK_L;

        // ---- fused MFMA phase
        f32x4 acc[2][4];
        f32x4 macc0 = (f32x4){0.f, 0.f, 0.f, 0.f};   // mu chain
        f32x4 macc1 = (f32x4){0.f, 0.f, 0.f, 0.f};   // md chain
#pragma unroll
        for (int mt = 0; mt < 2; ++mt)
#pragma unroll
            for (int nt = 0; nt < 4; ++nt) acc[mt][nt] = (f32x4){0.f, 0.f, 0.f, 0.f};

        // -- PREFETCH pm A-frags (L3 latency hides under the MFMA loop)
        f16x8 pAh[2][2], pAl[2][2];   // [h][mt]
        {
            int aP[2];
#pragma unroll
            for (int mt = 0; mt < 2; ++mt)
                aP[mt] = ((b0 + lw0 + mt) * 16 + m16) * 64 + quad * 8;
#pragma unroll
            for (int h = 0; h < 2; ++h)
#pragma unroll
                for (int mt = 0; mt < 2; ++mt) {
                    pAh[h][mt] = *(const f16x8*)(pmH + aP[mt] + h * 32);
                    pAl[h][mt] = *(const f16x8*)(pmL + aP[mt] + h * 32);
                }
        }

        const _Float16* Bhw = Bh + (size_t)(wv4 * 4) * 512 + (size_t)lane * 8;
        const _Float16* Blw = Bl + (size_t)(wv4 * 4) * 512 + (size_t)lane * 8;
        const _Float16* mBh = mBhi + (size_t)l * MBK_L + (size_t)wv * 512 + (size_t)lane * 8;
        const _Float16* mBl = mBlo + (size_t)l * MBK_L + (size_t)wv * 512 + (size_t)lane * 8;
        const f16x8 z16 = (f16x8){0, 0, 0, 0, 0, 0, 0, 0};

#pragma unroll
        for (int kc = 0; kc < 8; ++kc) {
            // -- mean-GEMM sub-steps: independent mu/md accumulator chains
#pragma unroll
            for (int hh = 0; hh < 2; ++hh) {
                const int kk0  = kc * 32 + quad * 8;
                const int mrow = hh * 8 + (m16 & 7);
                f16x8 mah = *(const f16x8*)&mH[mrow][kk0];
                f16x8 mal = *(const f16x8*)&mL[mrow][kk0];
                if (m16 >= 8) { mah = z16; mal = z16; }
                const size_t mo = (size_t)(hh * 8 + kc) * 8192;
                f16x8 bh = *(const f16x8*)(mBh + mo);
                f16x8 bl = *(const f16x8*)(mBl + mo);
                if (hh == 0) {
                    macc0 = __builtin_amdgcn_mfma_f32_16x16x32_f16(mah, bh, macc0, 0, 0, 0);
                    macc0 = __builtin_amdgcn_mfma_f32_16x16x32_f16(mah, bl, macc0, 0, 0, 0);
                    macc0 = __builtin_amdgcn_mfma_f32_16x16x32_f16(mal, bh, macc0, 0, 0, 0);
                } else {
                    macc1 = __builtin_amdgcn_mfma_f32_16x16x32_f16(mah, bh, macc1, 0, 0, 0);
                    macc1 = __builtin_amdgcn_mfma_f32_16x16x32_f16(mah, bl, macc1, 0, 0, 0);
                    macc1 = __builtin_amdgcn_mfma_f32_16x16x32_f16(mal, bh, macc1, 0, 0, 0);
                }
            }
            // -- s-part step kc
            f16x8 ah[2], al[2];
#pragma unroll
            for (int mt = 0; mt < 2; ++mt) {
                const int row = (lw0 + mt) * 16 + m16;
                ah[mt] = *(const f16x8*)&sH[row][kc * 32 + quad * 8];
                al[mt] = *(const f16x8*)&sL[row][kc * 32 + quad * 8];
            }
#pragma unroll
            for (int nt = 0; nt < 4; ++nt) {
                f16x8 bh = *(const f16x8*)(Bhw + (size_t)kc * 8192 + nt * 512);
                f16x8 bl = *(const f16x8*)(Blw + (size_t)kc * 8192 + nt * 512);
#pragma unroll
                for (int mt = 0; mt < 2; ++mt) {
                    acc[mt][nt] = __builtin_amdgcn_mfma_f32_16x16x32_f16(ah[mt], bh, acc[mt][nt], 0, 0, 0);
                    acc[mt][nt] = __builtin_amdgcn_mfma_f32_16x16x32_f16(ah[mt], bl, acc[mt][nt], 0, 0, 0);
                    acc[mt][nt] = __builtin_amdgcn_mfma_f32_16x16x32_f16(al[mt], bh, acc[mt][nt], 0, 0, 0);
                }
            }
        }
        // -- p-part: kc 8..9 (pu, pd) from the prefetched registers
#pragma unroll
        for (int h = 0; h < 2; ++h) {
#pragma unroll
            for (int nt = 0; nt < 4; ++nt) {
                f16x8 bh = *(const f16x8*)(Bhw + (size_t)(8 + h) * 8192 + nt * 512);
                f16x8 bl = *(const f16x8*)(Blw + (size_t)(8 + h) * 8192 + nt * 512);
#pragma unroll
                for (int mt = 0; mt < 2; ++mt) {
                    acc[mt][nt] = __builtin_amdgcn_mfma_f32_16x16x32_f16(pAh[h][mt], bh, acc[mt][nt], 0, 0, 0);
                    acc[mt][nt] = __builtin_amdgcn_mfma_f32_16x16x32_f16(pAh[h][mt], bl, acc[mt][nt], 0, 0, 0);
                    acc[mt][nt] = __builtin_amdgcn_mfma_f32_16x16x32_f16(pAl[h][mt], bh, acc[mt][nt], 0, 0, 0);
                }
            }
        }
        // -- Z write: D rows 0..7 (quad 0,1) = walkers 0..7
        if (quad < 2) {
            const int n = wv * 16 + m16;
            const float bv = bias[n];
#pragma unroll
            for (int reg = 0; reg < 4; ++reg)
                ZshL[quad * 4 + reg][n] = bv + (macc0[reg] + macc1[reg]);
        }
        __syncthreads();   // B2: ZshL ready, all sH/sL/mH/mL reads complete

        // ---- epilogue (tanh + residual from LDS) with FUSED next-layer means
#pragma unroll
        for (int mt = 0; mt < 2; ++mt) {
#pragma unroll
            for (int nt = 0; nt < 4; ++nt) {
                const int n  = nb0 + nt * 16 + m16;
                const float zv = ZshL[lw0 + mt][n];
                float sum4 = 0.f;
#pragma unroll
                for (int reg = 0; reg < 4; ++reg) {
                    const int row = (lw0 + mt) * 16 + quad * 4 + reg;
                    float t = fast_tanh(acc[mt][nt][reg] + zv);
                    if (l != 4) t += (float)sH[row][n] + (float)sL[row][n];
                    sum4 += t;
                    _Float16 hi, lo; split16(t, hi, lo);
                    sH[row][n] = hi;
                    sL[row][n] = lo;
                }
                if (l != 4) {
                    float sum8 = sum4 + __shfl_xor(sum4, 16);
                    if ((quad & 1) == 0) {
                        const int mrow = (quad >> 1) * 8 + (lw0 + mt);
                        _Float16 hi, lo; split16(sum8 * 0.125f, hi, lo);
                        mH[mrow][n] = hi;
                        mL[mrow][n] = lo;
                    }
                }
            }
        }
        __syncthreads();   // B3: new s + means visible to next phase
    }

    // ======================= fused orbitals + slogdet =======================
    const int pg    = wv >> 2;        // walker pair 0..3
    const int ospin = (wv >> 1) & 1;
    const int nhalf = wv & 1;

    // envl -> aliased onto mH (means dead after layer-4 gemm)
    float* envp = (float*)&mH[0][0];      // [8][16]
    if (tid < 128) {
        const int w = tid >> 4, e = tid & 15;
        float ex = 0.f;
#pragma unroll
        for (int at = 0; at < 4; ++at) {
            float dx = r[(b0 + w) * 48 + e * 3 + 0] - a[at * 3 + 0];
            float dy = r[(b0 + w) * 48 + e * 3 + 1] - a[at * 3 + 1];
            float dz = r[(b0 + w) * 48 + e * 3 + 2] - a[at * 3 + 2];
            ex += __expf(-sqrtf(dx * dx + dy * dy + dz * dz));
        }
        envp[w * 16 + e] = ex;
    }

    // orbital GEMM: A rows from LDS s
    const int arow = (pg * 2 + (m16 >> 3)) * 16 + ospin * 8 + (m16 & 7);
    f32x4 oacc[4];
#pragma unroll
    for (int nt = 0; nt < 4; ++nt) oacc[nt] = (f32x4){0.f, 0.f, 0.f, 0.f};

#pragma unroll
    for (int kc = 0; kc < 8; ++kc) {
        f16x8 ah = *(const f16x8*)&sH[arow][kc * 32 + quad * 8];
        f16x8 al = *(const f16x8*)&sL[arow][kc * 32 + quad * 8];
#pragma unroll
        for (int nt = 0; nt < 4; ++nt) {
            const size_t bo = (((size_t)ospin * 8 + kc) * 8 + nhalf * 4 + nt) * 512 + (size_t)lane * 8;
            f16x8 bh = *(const f16x8*)(oBhi + bo);
            f16x8 bl = *(const f16x8*)(oBlo + bo);
            oacc[nt] = __builtin_amdgcn_mfma_f32_16x16x32_f16(ah, bh, oacc[nt], 0, 0, 0);
            oacc[nt] = __builtin_amdgcn_mfma_f32_16x16x32_f16(ah, bl, oacc[nt], 0, 0, 0);
            oacc[nt] = __builtin_amdgcn_mfma_f32_16x16x32_f16(al, bh, oacc[nt], 0, 0, 0);
            oacc[nt] = __builtin_amdgcn_mfma_f32_16x16x32_f16(al, bl, oacc[nt], 0, 0, 0);
        }
    }
    __syncthreads();   // all sH/sL A-reads + envl writes complete

    // scatter -> orbL aliased onto sH ([8][2][16][66] f32 = 67,584 B = exact fit)
    float* orbp = (float*)&sH[0][0];
    const float* bm = ospin ? wdb : wub;
#pragma unroll
    for (int nt = 0; nt < 4; ++nt) {
        const int c = nhalf * 64 + nt * 16 + m16;
        const float bv = bm[c];
        const int d = c & 15;
        const int jrow = c >> 4;
#pragma unroll
        for (int reg = 0; reg < 4; ++reg) {
            const int m = quad * 4 + reg;
            const int wl = pg * 2 + (m >> 3);
            const int el = m & 7;
            orbp[((wl * 2 + ospin) * 16 + d) * 66 + jrow * 8 + el] =
                (oacc[nt][reg] + bv) * envp[wl * 16 + ospin * 8 + el];
        }
    }
    __syncthreads();

    // determinants + lse: threads 0..127 = (walker w = tid>>4, det d = tid&15)
    if (tid < 128) {
        const int w = tid >> 4, d = tid & 15;
        float M[8][8];
#pragma unroll
        for (int rr = 0; rr < 8; ++rr)
#pragma unroll
            for (int cc = 0; cc < 8; ++cc)
                M[rr][cc] = orbp[((w * 2 + 0) * 16 + d) * 66 + rr * 8 + cc];
        float s1, l1; slogdet8(M, s1, l1);
#pragma unroll
        for (int rr = 0; rr < 8; ++rr)
#pragma unroll
            for (int cc = 0; cc < 8; ++cc)
                M[rr][cc] = orbp[((w * 2 + 1) * 16 + d) * 66 + rr * 8 + cc];
        float s2, l2; slogdet8(M, s2, l2);
        float sgn = s1 * s2;
        float ld  = l1 + l2;

        float m = ld;
        m = fmaxf(m, __shfl_xor(m, 1));
        m = fmaxf(m, __shfl_xor(m, 2));
        m = fmaxf(m, __shfl_xor(m, 4));
        m = fmaxf(m, __shfl_xor(m, 8));
        float sub = sgn * __expf(ld - m) * wfW[d];
        sub += __shfl_xor(sub, 1);
        sub += __shfl_xor(sub, 2);
        sub += __shfl_xor(sub, 4);
        sub += __shfl_xor(sub, 8);
        if (d == 0) out[b0 + w] = logf(fabsf(sub)) + m;
    }
}

// ---------------------------------------------------------------------------
extern "C" void kernel_launch(void* const* d_in, const int* in_sizes, int n_in,
                              void* d_out, int out_size, void* d_ws, size_t ws_size,
                              hipStream_t stream) {
    (void)in_sizes; (void)n_in; (void)out_size; (void)ws_size;
    const float* r   = (const float*)d_in[0];
    const float* a   = (const float*)d_in[1];
    const float* sW0 = (const float*)d_in[2];
    const float* sb0 = (const float*)d_in[3];
    const float* sW  = (const float*)d_in[4];
    const float* sb  = (const float*)d_in[5];
    const float* pW0 = (const float*)d_in[6];
    const float* pb0 = (const float*)d_in[7];
    const float* pW  = (const float*)d_in[8];
    const float* pb  = (const float*)d_in[9];
    const float* vW  = (const float*)d_in[10];
    const float* vb  = (const float*)d_in[11];
    const float* wuW = (const float*)d_in[12];
    const float* wub = (const float*)d_in[13];
    const float* wdW = (const float*)d_in[14];
    const float* wdb = (const float*)d_in[15];
    const float* wfW = (const float*)d_in[16];
    float* out = (float*)d_out;

    // workspace layout (bytes)
    char* wsb = (char*)d_ws;
    _Float16* pm_hi = (_Float16*)(wsb + 0);          // 20,971,520 (5 stages)
    _Float16* pm_lo = (_Float16*)(wsb + 20971520);   // 20,971,520
    _Float16* Bhi   = (_Float16*)(wsb + 41943040);   //    819,200
    _Float16* Blo   = (_Float16*)(wsb + 42762240);   //    819,200
    _Float16* pBhi  = (_Float16*)(wsb + 43581440);   //      8,192
    _Float16* pBlo  = (_Float16*)(wsb + 43589632);   //      8,192
    _Float16* oBhi  = (_Float16*)(wsb + 43597824);   //    131,072
    _Float16* oBlo  = (_Float16*)(wsb + 43728896);   //    131,072
    _Float16* mBhi  = (_Float16*)(wsb + 43859968);   //  1,310,720 (5 layers)
    _Float16* mBlo  = (_Float16*)(wsb + 45170688);   //  1,310,720
    // total 46,481,408 (< 79,691,776 known-safe)

    k_prep_all<<<150, 256, 0, stream>>>(sW, vW, pW, wuW, wdW,
                                        Bhi, Blo, pBhi, pBlo, oBhi, oBlo,
                                        mBhi, mBlo);
    k_pstream<<<NB * 4, 256, 0, stream>>>(r, pW0, pb0, pb, pBhi, pBlo, pm_hi, pm_lo);
    k_mega<<<NB / 8, 1024, 0, stream>>>(pm_hi, pm_lo, Bhi, Blo, mBhi, mBlo,
                                        sb, vb, sW0, sb0,
                                        r, a, oBhi, oBlo, wub, wdb, wfW, out);
}

// Round 14
// 324.485 us; speedup vs baseline: 1.0913x; 1.0093x over previous
//
#include <hip/hip_runtime.h>
#include <math.h>

#define NB 2048
#define PM_STAGE 2097152   // elements per pmeans stage (2048*16*2*32)
#define BPK_L    81920     // elements per packed weight layer (10*16*64*8)
#define MBK_L    131072    // elements per packed mean-W layer (16*16*64*8)

typedef float    f32x4 __attribute__((ext_vector_type(4)));
typedef _Float16 f16x8 __attribute__((ext_vector_type(8)));
typedef _Float16 f16x4 __attribute__((ext_vector_type(4)));

__device__ __forceinline__ float fast_tanh(float x) {
    float ax = fabsf(x);
    float e  = __expf(2.0f * ax);
    float t  = 1.0f - 2.0f / (e + 1.0f);
    return copysignf(t, x);
}

__device__ __forceinline__ void split16(float x, _Float16& hi, _Float16& lo) {
    hi = (_Float16)x;
    lo = (_Float16)(x - (float)hi);
}

// ---------------------------------------------------------------------------
// MERGED one-time weight packs, 4x MORE PARALLEL than R13 (556 blocks vs 150;
// was 0.6 blocks/CU = latency-bound). Same values to same offsets:
//   blk   0..199  per-electron W   (ob = blk>>2, ntl = blk&3)
//   blk 200..203  p-layer W
//   blk 204..235  orbital W        (ob2 = blk-204: spin, kc, t)
//   blk 236..555  mean-W 5 layers  (mb = blk-236: unit = mb>>2, ntl = mb&3)
// ---------------------------------------------------------------------------
__global__ __launch_bounds__(256) void k_prep_all(
    const float* __restrict__ sW, const float* __restrict__ vW,
    const float* __restrict__ pW,
    const float* __restrict__ wuW, const float* __restrict__ wdW,
    _Float16* __restrict__ Bhi, _Float16* __restrict__ Blo,
    _Float16* __restrict__ pBhi, _Float16* __restrict__ pBlo,
    _Float16* __restrict__ oBhi, _Float16* __restrict__ oBlo,
    _Float16* __restrict__ mBhi, _Float16* __restrict__ mBlo)
{
    const int blk  = blockIdx.x;
    const int lane = threadIdx.x & 63;
    const int sub  = threadIdx.x >> 6;

    if (blk < 200) {
        const int ob  = blk >> 2;        // l*10 + kc
        const int ntl = blk & 3;
        const int l   = ob / 10;
        const int kc  = ob % 10;
        const float* Wsrc = (l < 4) ? (sW + (size_t)l * 212992) : vW;
        const size_t base = (size_t)l * BPK_L + (size_t)kc * 8192;
        const int nt = sub * 4 + ntl;
        const int n  = nt * 16 + (lane & 15);
#pragma unroll
        for (int j = 0; j < 8; ++j) {
            const int f = kc * 32 + (lane >> 4) * 8 + j;   // 0..319
            int row;
            if (f < 256)      row = f;
            else if (f < 288) row = 768 + (f - 256);
            else              row = 800 + (f - 288);
            const float w = Wsrc[row * 256 + n];
            _Float16 hi, lo; split16(w, hi, lo);
            Bhi[base + (size_t)(nt * 64 + lane) * 8 + j] = hi;
            Blo[base + (size_t)(nt * 64 + lane) * 8 + j] = lo;
        }
    } else if (blk < 204) {
        if (threadIdx.x < 128) {
            const int l   = blk - 200;
            const int nt  = threadIdx.x >> 6;
            const int m16 = lane & 15, quad = lane >> 4;
#pragma unroll
            for (int j = 0; j < 8; ++j) {
                float w = pW[l * 1024 + (quad * 8 + j) * 32 + nt * 16 + m16];
                _Float16 hi, lo; split16(w, hi, lo);
                pBhi[((size_t)l * 2 + nt) * 512 + lane * 8 + j] = hi;
                pBlo[((size_t)l * 2 + nt) * 512 + lane * 8 + j] = lo;
            }
        }
    } else if (blk < 236) {
        const int ob2  = blk - 204;      // spin*16 + kc*2 + t
        const int spin = ob2 >> 4;
        const int kc   = (ob2 >> 1) & 7;
        const int t    = ob2 & 1;
        const float* W = spin ? wdW : wuW;
        const int nt = sub * 2 + t;
        const int n  = nt * 16 + (lane & 15);
#pragma unroll
        for (int j = 0; j < 8; ++j) {
            const int k = kc * 32 + (lane >> 4) * 8 + j;
            float w = W[k * 128 + n];
            _Float16 hi, lo; split16(w, hi, lo);
            const size_t o = (((size_t)spin * 8 + kc) * 8 + nt) * 512 + (size_t)lane * 8 + j;
            oBhi[o] = hi; oBlo[o] = lo;
        }
    } else {
        const int mb   = blk - 236;      // (l*16 + kk)*4 + ntl
        const int unit = mb >> 2;
        const int ntl  = mb & 3;
        const int l    = unit >> 4;
        const int kk   = unit & 15;      // hh*8 + kc
        const float* Wsrc = (l < 4) ? (sW + (size_t)l * 212992) : vW;
        const size_t base = (size_t)l * MBK_L + (size_t)kk * 8192;
        const int nt = sub * 4 + ntl;
        const int n  = nt * 16 + (lane & 15);
#pragma unroll
        for (int j = 0; j < 8; ++j) {
            const int row = 256 + kk * 32 + (lane >> 4) * 8 + j;
            const float w = Wsrc[row * 256 + n];
            _Float16 hi, lo; split16(w, hi, lo);
            mBhi[base + (size_t)(nt * 64 + lane) * 8 + j] = hi;
            mBlo[base + (size_t)(nt * 64 + lane) * 8 + j] = lo;
        }
    }
}

// ---------------------------------------------------------------------------
// p-stream via split-f16 MFMA (3-term), barrier-free (R1-verbatim, verified).
// ---------------------------------------------------------------------------
__global__ __launch_bounds__(256) void k_pstream(
    const float* __restrict__ r,
    const float* __restrict__ pW0, const float* __restrict__ pb0,
    const float* __restrict__ pb,
    const _Float16* __restrict__ pBhi, const _Float16* __restrict__ pBlo,
    _Float16* __restrict__ pm_hi, _Float16* __restrict__ pm_lo)
{
    const int b    = blockIdx.x >> 2;
    const int jg   = blockIdx.x & 3;
    const int tid  = threadIdx.x;
    const int lane = tid & 63;
    const int wvl  = tid >> 6;           // 0..3
    const int j    = jg * 4 + wvl;       // this wave's j column (0..15)
    const int m16  = lane & 15;
    const int quad = lane >> 4;

    __shared__ float rl[48];
    __shared__ float pst[4][32][17];     // wave-private slices, stride 17 (odd)

    if (tid < 48) rl[tid] = r[b * 48 + tid];
    __syncthreads();                     // only barrier in the kernel

    const float rjx = rl[j * 3 + 0];
    const float rjy = rl[j * 3 + 1];
    const float rjz = rl[j * 3 + 2];

    const int f0 = m16, f1 = m16 + 16;
    float pcur[2][4];   // [nt][reg], D-layout residual state (rows i = quad*4+reg)

    // ---- layer 0
#pragma unroll
    for (int reg = 0; reg < 4; ++reg) {
        const int i = quad * 4 + reg;
        float dx = rjx - rl[i * 3 + 0];
        float dy = rjy - rl[i * 3 + 1];
        float dz = rjz - rl[i * 3 + 2];
        float ee = (i == j) ? 1.0f : 0.0f;
        float len = sqrtf((dx + ee) * (dx + ee) + (dy + ee) * (dy + ee) + (dz + ee) * (dz + ee));
#pragma unroll
        for (int nt = 0; nt < 2; ++nt) {
            const int k = nt ? f1 : f0;
            float acc = pb0[k] + dx * pW0[k] + dy * pW0[32 + k]
                      + dz * pW0[64 + k] + len * pW0[96 + k];
            float v = fast_tanh(acc);
            pcur[nt][reg] = v;
            pst[wvl][k][i] = v;
        }
    }
    asm volatile("s_waitcnt lgkmcnt(0)" ::: "memory");

    // ---- stage-0 means
    {
        const int mh = lane >> 5, mk = lane & 31;
        float s = 0.f;
#pragma unroll
        for (int i8 = 0; i8 < 8; ++i8) s += pst[wvl][mk][mh * 8 + i8];
        _Float16 hi, lo; split16(s * 0.125f, hi, lo);
        const size_t o = (size_t)b * 1024 + j * 64 + lane;
        pm_hi[o] = hi;
        pm_lo[o] = lo;
    }

    for (int l = 0; l < 4; ++l) {
        f16x8 ah, al;
#pragma unroll
        for (int jj = 0; jj < 8; ++jj) {
            float v = pst[wvl][quad * 8 + jj][m16];
            _Float16 hi, lo; split16(v, hi, lo);
            ah[jj] = hi; al[jj] = lo;
        }
        const _Float16* bhp = pBhi + ((size_t)l * 2) * 512 + (size_t)lane * 8;
        const _Float16* blp = pBlo + ((size_t)l * 2) * 512 + (size_t)lane * 8;
        f32x4 acc0 = (f32x4){0.f, 0.f, 0.f, 0.f};
        f32x4 acc1 = (f32x4){0.f, 0.f, 0.f, 0.f};
        {
            f16x8 bh = *(const f16x8*)(bhp);
            f16x8 bl = *(const f16x8*)(blp);
            acc0 = __builtin_amdgcn_mfma_f32_16x16x32_f16(ah, bh, acc0, 0, 0, 0);
            acc0 = __builtin_amdgcn_mfma_f32_16x16x32_f16(ah, bl, acc0, 0, 0, 0);
            acc0 = __builtin_amdgcn_mfma_f32_16x16x32_f16(al, bh, acc0, 0, 0, 0);
            bh = *(const f16x8*)(bhp + 512);
            bl = *(const f16x8*)(blp + 512);
            acc1 = __builtin_amdgcn_mfma_f32_16x16x32_f16(ah, bh, acc1, 0, 0, 0);
            acc1 = __builtin_amdgcn_mfma_f32_16x16x32_f16(ah, bl, acc1, 0, 0, 0);
            acc1 = __builtin_amdgcn_mfma_f32_16x16x32_f16(al, bh, acc1, 0, 0, 0);
        }
        const float b0v = pb[l * 32 + f0];
        const float b1v = pb[l * 32 + f1];
        asm volatile("" ::: "memory");
#pragma unroll
        for (int reg = 0; reg < 4; ++reg) {
            const int i = quad * 4 + reg;
            pcur[0][reg] += fast_tanh(acc0[reg] + b0v);
            pcur[1][reg] += fast_tanh(acc1[reg] + b1v);
            pst[wvl][f0][i] = pcur[0][reg];
            pst[wvl][f1][i] = pcur[1][reg];
        }
        asm volatile("s_waitcnt lgkmcnt(0)" ::: "memory");
        {
            const int mh = lane >> 5, mk = lane & 31;
            float s = 0.f;
#pragma unroll
            for (int i8 = 0; i8 < 8; ++i8) s += pst[wvl][mk][mh * 8 + i8];
            _Float16 hi, lo; split16(s * 0.125f, hi, lo);
            const size_t o = (size_t)(l + 1) * PM_STAGE + (size_t)b * 1024 + j * 64 + lane;
            pm_hi[o] = hi;
            pm_lo[o] = lo;
        }
    }
}

// ---------------------------------------------------------------------------
__device__ __forceinline__ void slogdet8(float M[8][8], float& sgn_out, float& ld_out) {
    float sgn = 1.f, ld = 0.f;
#pragma unroll
    for (int k = 0; k < 8; ++k) {
        float best = fabsf(M[k][k]);
        int p = k;
#pragma unroll
        for (int rr = k + 1; rr < 8; ++rr) {
            float v = fabsf(M[rr][k]);
            if (v > best) { best = v; p = rr; }
        }
        if (p != k) sgn = -sgn;
#pragma unroll
        for (int rr = k + 1; rr < 8; ++rr) {
            bool sw = (rr == p);
#pragma unroll
            for (int cc = k; cc < 8; ++cc) {
                float x = M[k][cc], y = M[rr][cc];
                M[k][cc]  = sw ? y : x;
                M[rr][cc] = sw ? x : y;
            }
        }
        float piv = M[k][k];
        if (piv < 0.f) sgn = -sgn;
        ld += logf(fabsf(piv));
        float inv = 1.f / piv;
#pragma unroll
        for (int rr = k + 1; rr < 8; ++rr) {
            float f = M[rr][k] * inv;
#pragma unroll
            for (int cc = k + 1; cc < 8; ++cc) M[rr][cc] -= f * M[k][cc];
        }
    }
    sgn_out = sgn; ld_out = ld;
}

// ---------------------------------------------------------------------------
// MEGA v13: R13-verbatim (verified at 197.7 us; VALU 44 / MFMA 23, no spill).
// ---------------------------------------------------------------------------
#define SROW 264
#define MROW 272

__global__ __launch_bounds__(1024, 4) void k_mega(
    const _Float16* __restrict__ pm_hi, const _Float16* __restrict__ pm_lo,
    const _Float16* __restrict__ Bhi, const _Float16* __restrict__ Blo,
    const _Float16* __restrict__ mBhi, const _Float16* __restrict__ mBlo,
    const float* __restrict__ sb, const float* __restrict__ vb,
    const float* __restrict__ sW0, const float* __restrict__ sb0,
    const float* __restrict__ r, const float* __restrict__ a,
    const _Float16* __restrict__ oBhi, const _Float16* __restrict__ oBlo,
    const float* __restrict__ wub, const float* __restrict__ wdb,
    const float* __restrict__ wfW,
    float* __restrict__ out)
{
    const int tid  = threadIdx.x;
    const int lane = tid & 63;
    const int wv   = tid >> 6;        // 0..15
    const int wg   = wv >> 2;         // walker pair group 0..3 (s-GEMM)
    const int wv4  = wv & 3;          // n-tile group (s-GEMM)
    const int m16  = lane & 15;
    const int quad = lane >> 4;
    const int b0   = blockIdx.x * 8;
    const int lw0  = wg * 2;          // local walkers lw0, lw0+1 (0..7)
    const int nb0  = wv4 * 64;

    __shared__ _Float16 sH[128][SROW];    // 67,584 B  [walker*16+e][k]
    __shared__ _Float16 sL[128][SROW];    // 67,584 B
    __shared__ _Float16 mH[16][MROW];     //  8,704 B  rows: mu w0..7, md w0..7
    __shared__ _Float16 mL[16][MROW];     //  8,704 B
    __shared__ float    ZshL[8][256];     //  8,192 B
    // total 160,768 B -> 1 block/CU, 16 waves

    // ========== prologue: fused k_s0 (embedding + first s layer, 8 walkers) ==
    {
        char*  sbase = (char*)&sH[0][0];
        float* pinA  = (float*)sbase;              // [8][16][16][4] 32,768 B (in sH)
        float* blkA  = (float*)(sbase + 32768);    // [8][16][56]    28,672 B (in sH)
        float* seA   = (float*)&ZshL[0][0];        // [8][16][16]     8,192 B (= ZshL)
        float* rlA   = (float*)&mH[0][0];          // [8][48] = 1,536 B
        float* alA   = rlA + 384;                  // [12]
        float* sm0A  = alA + 16;                   // [8][2][16] 1,024 B
        float* pm0A  = (float*)&mL[0][0];          // [8][16][2][4] 4,096 B

        if (tid < 384) rlA[tid] = r[(size_t)b0 * 48 + tid];
        if (tid >= 384 && tid < 396) alA[tid - 384] = a[tid - 384];
        __syncthreads();

#pragma unroll
        for (int it = 0; it < 2; ++it) {
            const int task = it * 1024 + tid;
            const int w = task >> 8, jj = (task >> 4) & 15, i = task & 15;
            const float* rw = rlA + w * 48;
            float dx = rw[jj * 3 + 0] - rw[i * 3 + 0];
            float dy = rw[jj * 3 + 1] - rw[i * 3 + 1];
            float dz = rw[jj * 3 + 2] - rw[i * 3 + 2];
            float ee = (i == jj) ? 1.0f : 0.0f;
            float len = sqrtf((dx + ee) * (dx + ee) + (dy + ee) * (dy + ee) + (dz + ee) * (dz + ee));
            float* p = pinA + (((w * 16 + jj) * 16 + i) << 2);
            p[0] = dx; p[1] = dy; p[2] = dz; p[3] = len;
        }
        if (tid < 128) {
            const int w = tid >> 4, e = tid & 15;
            const float* rw = rlA + w * 48;
#pragma unroll
            for (int at = 0; at < 4; ++at) {
                float dx = rw[e * 3 + 0] - alA[at * 3 + 0];
                float dy = rw[e * 3 + 1] - alA[at * 3 + 1];
                float dz = rw[e * 3 + 2] - alA[at * 3 + 2];
                float ln = sqrtf(dx * dx + dy * dy + dz * dz);
                float* p = seA + (w * 16 + e) * 16 + at * 4;
                p[0] = dx; p[1] = dy; p[2] = dz; p[3] = ln;
            }
        }
        __syncthreads();

        if (tid < 256) {
            const int w = tid >> 5, h = (tid >> 4) & 1, f = tid & 15;
            float s = 0.f;
            for (int e = 0; e < 8; ++e) s += seA[(w * 16 + h * 8 + e) * 16 + f];
            sm0A[(w * 2 + h) * 16 + f] = s * 0.125f;
        }
        {
            const int w = tid >> 7, jj = (tid >> 3) & 15, h = (tid >> 2) & 1, f = tid & 3;
            float s = 0.f;
            for (int i2 = 0; i2 < 8; ++i2)
                s += pinA[(((w * 16 + jj) * 16 + h * 8 + i2) << 2) + f];
            pm0A[((w * 16 + jj) * 2 + h) * 4 + f] = s * 0.125f;
        }
        __syncthreads();

        for (int t = tid; t < 8 * 16 * 56; t += 1024) {
            const int w = t / 896, rem = t % 896, e = rem / 56, k = rem % 56;
            float v;
            if (k < 16)      v = seA[(w * 16 + e) * 16 + k];
            else if (k < 32) v = sm0A[(w * 2 + 0) * 16 + (k - 16)];
            else if (k < 48) v = sm0A[(w * 2 + 1) * 16 + (k - 32)];
            else if (k < 52) v = pm0A[((w * 16 + e) * 2 + 0) * 4 + (k - 48)];
            else             v = pm0A[((w * 16 + e) * 2 + 1) * 4 + (k - 52)];
            blkA[(w * 16 + e) * 56 + k] = v;
        }
        __syncthreads();

        // GEMV (k_s0-identical per walker): thread = (col n0, walkers wsel/wsel+4)
        const int n0 = tid & 255, wsel = tid >> 8;   // 0..3
        float accA[16], accB[16];
#pragma unroll
        for (int e = 0; e < 16; ++e) { accA[e] = sb0[n0]; accB[e] = sb0[n0]; }
        for (int k = 0; k < 56; k += 4) {
            float w0 = sW0[(k + 0) * 256 + n0];
            float w1 = sW0[(k + 1) * 256 + n0];
            float w2 = sW0[(k + 2) * 256 + n0];
            float w3 = sW0[(k + 3) * 256 + n0];
#pragma unroll
            for (int e = 0; e < 16; ++e) {
                float4 sa = *(const float4*)&blkA[((wsel    ) * 16 + e) * 56 + k];
                float4 sc = *(const float4*)&blkA[((wsel + 4) * 16 + e) * 56 + k];
                accA[e] += sa.x * w0 + sa.y * w1 + sa.z * w2 + sa.w * w3;
                accB[e] += sc.x * w0 + sc.y * w1 + sc.z * w2 + sc.w * w3;
            }
        }
        __syncthreads();   // all blk/se reads complete before sH/sL overwrite

#pragma unroll
        for (int e = 0; e < 16; ++e) {
            _Float16 hi, lo;
            split16(fast_tanh(accA[e]), hi, lo);
            sH[wsel * 16 + e][n0] = hi;
            sL[wsel * 16 + e][n0] = lo;
            split16(fast_tanh(accB[e]), hi, lo);
            sH[(wsel + 4) * 16 + e][n0] = hi;
            sL[(wsel + 4) * 16 + e][n0] = lo;
        }
    }
    __syncthreads();

    // ========== means for layer 0 (reads rounded s) ==========
    {
        const int w  = tid >> 7;          // 0..7
        const int h  = (tid >> 6) & 1;
        const int k0 = (tid & 63) * 4;
        float s0 = 0.f, s1 = 0.f, s2 = 0.f, s3 = 0.f;
#pragma unroll
        for (int e = 0; e < 8; ++e) {
            const int row = w * 16 + h * 8 + e;
            f16x4 hv = *(const f16x4*)&sH[row][k0];
            f16x4 lv = *(const f16x4*)&sL[row][k0];
            s0 += (float)hv[0] + (float)lv[0];
            s1 += (float)hv[1] + (float)lv[1];
            s2 += (float)hv[2] + (float)lv[2];
            s3 += (float)hv[3] + (float)lv[3];
        }
        const int mrow = h * 8 + w;
        f16x4 hq, lq;
        _Float16 hi, lo;
        split16(s0 * 0.125f, hi, lo); hq[0] = hi; lq[0] = lo;
        split16(s1 * 0.125f, hi, lo); hq[1] = hi; lq[1] = lo;
        split16(s2 * 0.125f, hi, lo); hq[2] = hi; lq[2] = lo;
        split16(s3 * 0.125f, hi, lo); hq[3] = hi; lq[3] = lo;
        *(f16x4*)&mH[mrow][k0] = hq;
        *(f16x4*)&mL[mrow][k0] = lq;
    }
    __syncthreads();   // B1 (once)

    for (int l = 0; l < 5; ++l) {
        const float* bias = (l < 4) ? (sb + l * 256) : vb;
        const _Float16* pmH = pm_hi + (size_t)l * PM_STAGE;
        const _Float16* pmL = pm_lo + (size_t)l * PM_STAGE;
        const _Float16* Bh  = Bhi + (size_t)l * BPK_L;
        const _Float16* Bl  = Blo + (size_t)l * BPK_L;

        // ---- fused MFMA phase
        f32x4 acc[2][4];
        f32x4 macc0 = (f32x4){0.f, 0.f, 0.f, 0.f};   // mu chain
        f32x4 macc1 = (f32x4){0.f, 0.f, 0.f, 0.f};   // md chain
#pragma unroll
        for (int mt = 0; mt < 2; ++mt)
#pragma unroll
            for (int nt = 0; nt < 4; ++nt) acc[mt][nt] = (f32x4){0.f, 0.f, 0.f, 0.f};

        // -- PREFETCH pm A-frags (L3 latency hides under the MFMA loop)
        f16x8 pAh[2][2], pAl[2][2];   // [h][mt]
        {
            int aP[2];
#pragma unroll
            for (int mt = 0; mt < 2; ++mt)
                aP[mt] = ((b0 + lw0 + mt) * 16 + m16) * 64 + quad * 8;
#pragma unroll
            for (int h = 0; h < 2; ++h)
#pragma unroll
                for (int mt = 0; mt < 2; ++mt) {
                    pAh[h][mt] = *(const f16x8*)(pmH + aP[mt] + h * 32);
                    pAl[h][mt] = *(const f16x8*)(pmL + aP[mt] + h * 32);
                }
        }

        const _Float16* Bhw = Bh + (size_t)(wv4 * 4) * 512 + (size_t)lane * 8;
        const _Float16* Blw = Bl + (size_t)(wv4 * 4) * 512 + (size_t)lane * 8;
        const _Float16* mBh = mBhi + (size_t)l * MBK_L + (size_t)wv * 512 + (size_t)lane * 8;
        const _Float16* mBl = mBlo + (size_t)l * MBK_L + (size_t)wv * 512 + (size_t)lane * 8;
        const f16x8 z16 = (f16x8){0, 0, 0, 0, 0, 0, 0, 0};

#pragma unroll
        for (int kc = 0; kc < 8; ++kc) {
            // -- mean-GEMM sub-steps: independent mu/md accumulator chains
#pragma unroll
            for (int hh = 0; hh < 2; ++hh) {
                const int kk0  = kc * 32 + quad * 8;
                const int mrow = hh * 8 + (m16 & 7);
                f16x8 mah = *(const f16x8*)&mH[mrow][kk0];
                f16x8 mal = *(const f16x8*)&mL[mrow][kk0];
                if (m16 >= 8) { mah = z16; mal = z16; }
                const size_t mo = (size_t)(hh * 8 + kc) * 8192;
                f16x8 bh = *(const f16x8*)(mBh + mo);
                f16x8 bl = *(const f16x8*)(mBl + mo);
                if (hh == 0) {
                    macc0 = __builtin_amdgcn_mfma_f32_16x16x32_f16(mah, bh, macc0, 0, 0, 0);
                    macc0 = __builtin_amdgcn_mfma_f32_16x16x32_f16(mah, bl, macc0, 0, 0, 0);
                    macc0 = __builtin_amdgcn_mfma_f32_16x16x32_f16(mal, bh, macc0, 0, 0, 0);
                } else {
                    macc1 = __builtin_amdgcn_mfma_f32_16x16x32_f16(mah, bh, macc1, 0, 0, 0);
                    macc1 = __builtin_amdgcn_mfma_f32_16x16x32_f16(mah, bl, macc1, 0, 0, 0);
                    macc1 = __builtin_amdgcn_mfma_f32_16x16x32_f16(mal, bh, macc1, 0, 0, 0);
                }
            }
            // -- s-part step kc
            f16x8 ah[2], al[2];
#pragma unroll
            for (int mt = 0; mt < 2; ++mt) {
                const int row = (lw0 + mt) * 16 + m16;
                ah[mt] = *(const f16x8*)&sH[row][kc * 32 + quad * 8];
                al[mt] = *(const f16x8*)&sL[row][kc * 32 + quad * 8];
            }
#pragma unroll
            for (int nt = 0; nt < 4; ++nt) {
                f16x8 bh = *(const f16x8*)(Bhw + (size_t)kc * 8192 + nt * 512);
                f16x8 bl = *(const f16x8*)(Blw + (size_t)kc * 8192 + nt * 512);
#pragma unroll
                for (int mt = 0; mt < 2; ++mt) {
                    acc[mt][nt] = __builtin_amdgcn_mfma_f32_16x16x32_f16(ah[mt], bh, acc[mt][nt], 0, 0, 0);
                    acc[mt][nt] = __builtin_amdgcn_mfma_f32_16x16x32_f16(ah[mt], bl, acc[mt][nt], 0, 0, 0);
                    acc[mt][nt] = __builtin_amdgcn_mfma_f32_16x16x32_f16(al[mt], bh, acc[mt][nt], 0, 0, 0);
                }
            }
        }
        // -- p-part: kc 8..9 (pu, pd) from the prefetched registers
#pragma unroll
        for (int h = 0; h < 2; ++h) {
#pragma unroll
            for (int nt = 0; nt < 4; ++nt) {
                f16x8 bh = *(const f16x8*)(Bhw + (size_t)(8 + h) * 8192 + nt * 512);
                f16x8 bl = *(const f16x8*)(Blw + (size_t)(8 + h) * 8192 + nt * 512);
#pragma unroll
                for (int mt = 0; mt < 2; ++mt) {
                    acc[mt][nt] = __builtin_amdgcn_mfma_f32_16x16x32_f16(pAh[h][mt], bh, acc[mt][nt], 0, 0, 0);
                    acc[mt][nt] = __builtin_amdgcn_mfma_f32_16x16x32_f16(pAh[h][mt], bl, acc[mt][nt], 0, 0, 0);
                    acc[mt][nt] = __builtin_amdgcn_mfma_f32_16x16x32_f16(pAl[h][mt], bh, acc[mt][nt], 0, 0, 0);
                }
            }
        }
        // -- Z write: D rows 0..7 (quad 0,1) = walkers 0..7
        if (quad < 2) {
            const int n = wv * 16 + m16;
            const float bv = bias[n];
#pragma unroll
            for (int reg = 0; reg < 4; ++reg)
                ZshL[quad * 4 + reg][n] = bv + (macc0[reg] + macc1[reg]);
        }
        __syncthreads();   // B2: ZshL ready, all sH/sL/mH/mL reads complete

        // ---- epilogue (tanh + residual from LDS) with FUSED next-layer means
#pragma unroll
        for (int mt = 0; mt < 2; ++mt) {
#pragma unroll
            for (int nt = 0; nt < 4; ++nt) {
                const int n  = nb0 + nt * 16 + m16;
                const float zv = ZshL[lw0 + mt][n];
                float sum4 = 0.f;
#pragma unroll
                for (int reg = 0; reg < 4; ++reg) {
                    const int row = (lw0 + mt) * 16 + quad * 4 + reg;
                    float t = fast_tanh(acc[mt][nt][reg] + zv);
                    if (l != 4) t += (float)sH[row][n] + (float)sL[row][n];
                    sum4 += t;
                    _Float16 hi, lo; split16(t, hi, lo);
                    sH[row][n] = hi;
                    sL[row][n] = lo;
                }
                if (l != 4) {
                    float sum8 = sum4 + __shfl_xor(sum4, 16);
                    if ((quad & 1) == 0) {
                        const int mrow = (quad >> 1) * 8 + (lw0 + mt);
                        _Float16 hi, lo; split16(sum8 * 0.125f, hi, lo);
                        mH[mrow][n] = hi;
                        mL[mrow][n] = lo;
                    }
                }
            }
        }
        __syncthreads();   // B3: new s + means visible to next phase
    }

    // ======================= fused orbitals + slogdet =======================
    const int pg    = wv >> 2;        // walker pair 0..3
    const int ospin = (wv >> 1) & 1;
    const int nhalf = wv & 1;

    // envl -> aliased onto mH (means dead after layer-4 gemm)
    float* envp = (float*)&mH[0][0];      // [8][16]
    if (tid < 128) {
        const int w = tid >> 4, e = tid & 15;
        float ex = 0.f;
#pragma unroll
        for (int at = 0; at < 4; ++at) {
            float dx = r[(b0 + w) * 48 + e * 3 + 0] - a[at * 3 + 0];
            float dy = r[(b0 + w) * 48 + e * 3 + 1] - a[at * 3 + 1];
            float dz = r[(b0 + w) * 48 + e * 3 + 2] - a[at * 3 + 2];
            ex += __expf(-sqrtf(dx * dx + dy * dy + dz * dz));
        }
        envp[w * 16 + e] = ex;
    }

    // orbital GEMM: A rows from LDS s
    const int arow = (pg * 2 + (m16 >> 3)) * 16 + ospin * 8 + (m16 & 7);
    f32x4 oacc[4];
#pragma unroll
    for (int nt = 0; nt < 4; ++nt) oacc[nt] = (f32x4){0.f, 0.f, 0.f, 0.f};

#pragma unroll
    for (int kc = 0; kc < 8; ++kc) {
        f16x8 ah = *(const f16x8*)&sH[arow][kc * 32 + quad * 8];
        f16x8 al = *(const f16x8*)&sL[arow][kc * 32 + quad * 8];
#pragma unroll
        for (int nt = 0; nt < 4; ++nt) {
            const size_t bo = (((size_t)ospin * 8 + kc) * 8 + nhalf * 4 + nt) * 512 + (size_t)lane * 8;
            f16x8 bh = *(const f16x8*)(oBhi + bo);
            f16x8 bl = *(const f16x8*)(oBlo + bo);
            oacc[nt] = __builtin_amdgcn_mfma_f32_16x16x32_f16(ah, bh, oacc[nt], 0, 0, 0);
            oacc[nt] = __builtin_amdgcn_mfma_f32_16x16x32_f16(ah, bl, oacc[nt], 0, 0, 0);
            oacc[nt] = __builtin_amdgcn_mfma_f32_16x16x32_f16(al, bh, oacc[nt], 0, 0, 0);
            oacc[nt] = __builtin_amdgcn_mfma_f32_16x16x32_f16(al, bl, oacc[nt], 0, 0, 0);
        }
    }
    __syncthreads();   // all sH/sL A-reads + envl writes complete

    // scatter -> orbL aliased onto sH ([8][2][16][66] f32 = 67,584 B = exact fit)
    float* orbp = (float*)&sH[0][0];
    const float* bm = ospin ? wdb : wub;
#pragma unroll
    for (int nt = 0; nt < 4; ++nt) {
        const int c = nhalf * 64 + nt * 16 + m16;
        const float bv = bm[c];
        const int d = c & 15;
        const int jrow = c >> 4;
#pragma unroll
        for (int reg = 0; reg < 4; ++reg) {
            const int m = quad * 4 + reg;
            const int wl = pg * 2 + (m >> 3);
            const int el = m & 7;
            orbp[((wl * 2 + ospin) * 16 + d) * 66 + jrow * 8 + el] =
                (oacc[nt][reg] + bv) * envp[wl * 16 + ospin * 8 + el];
        }
    }
    __syncthreads();

    // determinants + lse: threads 0..127 = (walker w = tid>>4, det d = tid&15)
    if (tid < 128) {
        const int w = tid >> 4, d = tid & 15;
        float M[8][8];
#pragma unroll
        for (int rr = 0; rr < 8; ++rr)
#pragma unroll
            for (int cc = 0; cc < 8; ++cc)
                M[rr][cc] = orbp[((w * 2 + 0) * 16 + d) * 66 + rr * 8 + cc];
        float s1, l1; slogdet8(M, s1, l1);
#pragma unroll
        for (int rr = 0; rr < 8; ++rr)
#pragma unroll
            for (int cc = 0; cc < 8; ++cc)
                M[rr][cc] = orbp[((w * 2 + 1) * 16 + d) * 66 + rr * 8 + cc];
        float s2, l2; slogdet8(M, s2, l2);
        float sgn = s1 * s2;
        float ld  = l1 + l2;

        float m = ld;
        m = fmaxf(m, __shfl_xor(m, 1));
        m = fmaxf(m, __shfl_xor(m, 2));
        m = fmaxf(m, __shfl_xor(m, 4));
        m = fmaxf(m, __shfl_xor(m, 8));
        float sub = sgn * __expf(ld - m) * wfW[d];
        sub += __shfl_xor(sub, 1);
        sub += __shfl_xor(sub, 2);
        sub += __shfl_xor(sub, 4);
        sub += __shfl_xor(sub, 8);
        if (d == 0) out[b0 + w] = logf(fabsf(sub)) + m;
    }
}

// ---------------------------------------------------------------------------
extern "C" void kernel_launch(void* const* d_in, const int* in_sizes, int n_in,
                              void* d_out, int out_size, void* d_ws, size_t ws_size,
                              hipStream_t stream) {
    (void)in_sizes; (void)n_in; (void)out_size; (void)ws_size;
    const float* r   = (const float*)d_in[0];
    const float* a   = (const float*)d_in[1];
    const float* sW0 = (const float*)d_in[2];
    const float* sb0 = (const float*)d_in[3];
    const float* sW  = (const float*)d_in[4];
    const float* sb  = (const float*)d_in[5];
    const float* pW0 = (const float*)d_in[6];
    const float* pb0 = (const float*)d_in[7];
    const float* pW  = (const float*)d_in[8];
    const float* pb  = (const float*)d_in[9];
    const float* vW  = (const float*)d_in[10];
    const float* vb  = (const float*)d_in[11];
    const float* wuW = (const float*)d_in[12];
    const float* wub = (const float*)d_in[13];
    const float* wdW = (const float*)d_in[14];
    const float* wdb = (const float*)d_in[15];
    const float* wfW = (const float*)d_in[16];
    float* out = (float*)d_out;

    // workspace layout (bytes)
    char* wsb = (char*)d_ws;
    _Float16* pm_hi = (_Float16*)(wsb + 0);          // 20,971,520 (5 stages)
    _Float16* pm_lo = (_Float16*)(wsb + 20971520);   // 20,971,520
    _Float16* Bhi   = (_Float16*)(wsb + 41943040);   //    819,200
    _Float16* Blo   = (_Float16*)(wsb + 42762240);   //    819,200
    _Float16* pBhi  = (_Float16*)(wsb + 43581440);   //      8,192
    _Float16* pBlo  = (_Float16*)(wsb + 43589632);   //      8,192
    _Float16* oBhi  = (_Float16*)(wsb + 43597824);   //    131,072
    _Float16* oBlo  = (_Float16*)(wsb + 43728896);   //    131,072
    _Float16* mBhi  = (_Float16*)(wsb + 43859968);   //  1,310,720 (5 layers)
    _Float16* mBlo  = (_Float16*)(wsb + 45170688);   //  1,310,720
    // total 46,481,408 (< 79,691,776 known-safe)

    k_prep_all<<<556, 256, 0, stream>>>(sW, vW, pW, wuW, wdW,
                                        Bhi, Blo, pBhi, pBlo, oBhi, oBlo,
                                        mBhi, mBlo);
    k_pstream<<<NB * 4, 256, 0, stream>>>(r, pW0, pb0, pb, pBhi, pBlo, pm_hi, pm_lo);
    k_mega<<<NB / 8, 1024, 0, stream>>>(pm_hi, pm_lo, Bhi, Blo, mBhi, mBlo,
                                        sb, vb, sW0, sb0,
                                        r, a, oBhi, oBlo, wub, wdb, wfW, out);
}

// Round 15
// 300.383 us; speedup vs baseline: 1.1789x; 1.0802x over previous
//
#include <hip/hip_runtime.h>
#include <math.h>

#define NB 2048
#define PM_STAGE 2097152   // elements per pmeans stage (2048*16*2*32)
#define BPK_L    81920     // elements per packed weight layer (10*16*64*8)
#define MBK_L    131072    // elements per packed mean-W layer (16*16*64*8)

typedef float    f32x4 __attribute__((ext_vector_type(4)));
typedef _Float16 f16x8 __attribute__((ext_vector_type(8)));
typedef _Float16 f16x4 __attribute__((ext_vector_type(4)));

// v_rcp_f32-based tanh: replaces the IEEE div sequence (~10 VALU instr) with
// rcp+mul (~1 ulp; output perturbation ~1e-7, invisible vs f16-split error).
__device__ __forceinline__ float fast_tanh(float x) {
    float ax = fabsf(x);
    float e  = __expf(2.0f * ax);
    float t  = 1.0f - 2.0f * __builtin_amdgcn_rcpf(e + 1.0f);
    return copysignf(t, x);
}

__device__ __forceinline__ void split16(float x, _Float16& hi, _Float16& lo) {
    hi = (_Float16)x;
    lo = (_Float16)(x - (float)hi);
}

// ---------------------------------------------------------------------------
// MERGED one-time weight packs, 556 blocks (R14-verbatim, verified).
// ---------------------------------------------------------------------------
__global__ __launch_bounds__(256) void k_prep_all(
    const float* __restrict__ sW, const float* __restrict__ vW,
    const float* __restrict__ pW,
    const float* __restrict__ wuW, const float* __restrict__ wdW,
    _Float16* __restrict__ Bhi, _Float16* __restrict__ Blo,
    _Float16* __restrict__ pBhi, _Float16* __restrict__ pBlo,
    _Float16* __restrict__ oBhi, _Float16* __restrict__ oBlo,
    _Float16* __restrict__ mBhi, _Float16* __restrict__ mBlo)
{
    const int blk  = blockIdx.x;
    const int lane = threadIdx.x & 63;
    const int sub  = threadIdx.x >> 6;

    if (blk < 200) {
        const int ob  = blk >> 2;        // l*10 + kc
        const int ntl = blk & 3;
        const int l   = ob / 10;
        const int kc  = ob % 10;
        const float* Wsrc = (l < 4) ? (sW + (size_t)l * 212992) : vW;
        const size_t base = (size_t)l * BPK_L + (size_t)kc * 8192;
        const int nt = sub * 4 + ntl;
        const int n  = nt * 16 + (lane & 15);
#pragma unroll
        for (int j = 0; j < 8; ++j) {
            const int f = kc * 32 + (lane >> 4) * 8 + j;   // 0..319
            int row;
            if (f < 256)      row = f;
            else if (f < 288) row = 768 + (f - 256);
            else              row = 800 + (f - 288);
            const float w = Wsrc[row * 256 + n];
            _Float16 hi, lo; split16(w, hi, lo);
            Bhi[base + (size_t)(nt * 64 + lane) * 8 + j] = hi;
            Blo[base + (size_t)(nt * 64 + lane) * 8 + j] = lo;
        }
    } else if (blk < 204) {
        if (threadIdx.x < 128) {
            const int l   = blk - 200;
            const int nt  = threadIdx.x >> 6;
            const int m16 = lane & 15, quad = lane >> 4;
#pragma unroll
            for (int j = 0; j < 8; ++j) {
                float w = pW[l * 1024 + (quad * 8 + j) * 32 + nt * 16 + m16];
                _Float16 hi, lo; split16(w, hi, lo);
                pBhi[((size_t)l * 2 + nt) * 512 + lane * 8 + j] = hi;
                pBlo[((size_t)l * 2 + nt) * 512 + lane * 8 + j] = lo;
            }
        }
    } else if (blk < 236) {
        const int ob2  = blk - 204;      // spin*16 + kc*2 + t
        const int spin = ob2 >> 4;
        const int kc   = (ob2 >> 1) & 7;
        const int t    = ob2 & 1;
        const float* W = spin ? wdW : wuW;
        const int nt = sub * 2 + t;
        const int n  = nt * 16 + (lane & 15);
#pragma unroll
        for (int j = 0; j < 8; ++j) {
            const int k = kc * 32 + (lane >> 4) * 8 + j;
            float w = W[k * 128 + n];
            _Float16 hi, lo; split16(w, hi, lo);
            const size_t o = (((size_t)spin * 8 + kc) * 8 + nt) * 512 + (size_t)lane * 8 + j;
            oBhi[o] = hi; oBlo[o] = lo;
        }
    } else {
        const int mb   = blk - 236;      // (l*16 + kk)*4 + ntl
        const int unit = mb >> 2;
        const int ntl  = mb & 3;
        const int l    = unit >> 4;
        const int kk   = unit & 15;      // hh*8 + kc
        const float* Wsrc = (l < 4) ? (sW + (size_t)l * 212992) : vW;
        const size_t base = (size_t)l * MBK_L + (size_t)kk * 8192;
        const int nt = sub * 4 + ntl;
        const int n  = nt * 16 + (lane & 15);
#pragma unroll
        for (int j = 0; j < 8; ++j) {
            const int row = 256 + kk * 32 + (lane >> 4) * 8 + j;
            const float w = Wsrc[row * 256 + n];
            _Float16 hi, lo; split16(w, hi, lo);
            mBhi[base + (size_t)(nt * 64 + lane) * 8 + j] = hi;
            mBlo[base + (size_t)(nt * 64 + lane) * 8 + j] = lo;
        }
    }
}

// ---------------------------------------------------------------------------
// p-stream via split-f16 MFMA (3-term), barrier-free (R1-verbatim, verified).
// ---------------------------------------------------------------------------
__global__ __launch_bounds__(256) void k_pstream(
    const float* __restrict__ r,
    const float* __restrict__ pW0, const float* __restrict__ pb0,
    const float* __restrict__ pb,
    const _Float16* __restrict__ pBhi, const _Float16* __restrict__ pBlo,
    _Float16* __restrict__ pm_hi, _Float16* __restrict__ pm_lo)
{
    const int b    = blockIdx.x >> 2;
    const int jg   = blockIdx.x & 3;
    const int tid  = threadIdx.x;
    const int lane = tid & 63;
    const int wvl  = tid >> 6;           // 0..3
    const int j    = jg * 4 + wvl;       // this wave's j column (0..15)
    const int m16  = lane & 15;
    const int quad = lane >> 4;

    __shared__ float rl[48];
    __shared__ float pst[4][32][17];     // wave-private slices, stride 17 (odd)

    if (tid < 48) rl[tid] = r[b * 48 + tid];
    __syncthreads();                     // only barrier in the kernel

    const float rjx = rl[j * 3 + 0];
    const float rjy = rl[j * 3 + 1];
    const float rjz = rl[j * 3 + 2];

    const int f0 = m16, f1 = m16 + 16;
    float pcur[2][4];   // [nt][reg], D-layout residual state (rows i = quad*4+reg)

    // ---- layer 0
#pragma unroll
    for (int reg = 0; reg < 4; ++reg) {
        const int i = quad * 4 + reg;
        float dx = rjx - rl[i * 3 + 0];
        float dy = rjy - rl[i * 3 + 1];
        float dz = rjz - rl[i * 3 + 2];
        float ee = (i == j) ? 1.0f : 0.0f;
        float len = sqrtf((dx + ee) * (dx + ee) + (dy + ee) * (dy + ee) + (dz + ee) * (dz + ee));
#pragma unroll
        for (int nt = 0; nt < 2; ++nt) {
            const int k = nt ? f1 : f0;
            float acc = pb0[k] + dx * pW0[k] + dy * pW0[32 + k]
                      + dz * pW0[64 + k] + len * pW0[96 + k];
            float v = fast_tanh(acc);
            pcur[nt][reg] = v;
            pst[wvl][k][i] = v;
        }
    }
    asm volatile("s_waitcnt lgkmcnt(0)" ::: "memory");

    // ---- stage-0 means
    {
        const int mh = lane >> 5, mk = lane & 31;
        float s = 0.f;
#pragma unroll
        for (int i8 = 0; i8 < 8; ++i8) s += pst[wvl][mk][mh * 8 + i8];
        _Float16 hi, lo; split16(s * 0.125f, hi, lo);
        const size_t o = (size_t)b * 1024 + j * 64 + lane;
        pm_hi[o] = hi;
        pm_lo[o] = lo;
    }

    for (int l = 0; l < 4; ++l) {
        f16x8 ah, al;
#pragma unroll
        for (int jj = 0; jj < 8; ++jj) {
            float v = pst[wvl][quad * 8 + jj][m16];
            _Float16 hi, lo; split16(v, hi, lo);
            ah[jj] = hi; al[jj] = lo;
        }
        const _Float16* bhp = pBhi + ((size_t)l * 2) * 512 + (size_t)lane * 8;
        const _Float16* blp = pBlo + ((size_t)l * 2) * 512 + (size_t)lane * 8;
        f32x4 acc0 = (f32x4){0.f, 0.f, 0.f, 0.f};
        f32x4 acc1 = (f32x4){0.f, 0.f, 0.f, 0.f};
        {
            f16x8 bh = *(const f16x8*)(bhp);
            f16x8 bl = *(const f16x8*)(blp);
            acc0 = __builtin_amdgcn_mfma_f32_16x16x32_f16(ah, bh, acc0, 0, 0, 0);
            acc0 = __builtin_amdgcn_mfma_f32_16x16x32_f16(ah, bl, acc0, 0, 0, 0);
            acc0 = __builtin_amdgcn_mfma_f32_16x16x32_f16(al, bh, acc0, 0, 0, 0);
            bh = *(const f16x8*)(bhp + 512);
            bl = *(const f16x8*)(blp + 512);
            acc1 = __builtin_amdgcn_mfma_f32_16x16x32_f16(ah, bh, acc1, 0, 0, 0);
            acc1 = __builtin_amdgcn_mfma_f32_16x16x32_f16(ah, bl, acc1, 0, 0, 0);
            acc1 = __builtin_amdgcn_mfma_f32_16x16x32_f16(al, bh, acc1, 0, 0, 0);
        }
        const float b0v = pb[l * 32 + f0];
        const float b1v = pb[l * 32 + f1];
        asm volatile("" ::: "memory");
#pragma unroll
        for (int reg = 0; reg < 4; ++reg) {
            const int i = quad * 4 + reg;
            pcur[0][reg] += fast_tanh(acc0[reg] + b0v);
            pcur[1][reg] += fast_tanh(acc1[reg] + b1v);
            pst[wvl][f0][i] = pcur[0][reg];
            pst[wvl][f1][i] = pcur[1][reg];
        }
        asm volatile("s_waitcnt lgkmcnt(0)" ::: "memory");
        {
            const int mh = lane >> 5, mk = lane & 31;
            float s = 0.f;
#pragma unroll
            for (int i8 = 0; i8 < 8; ++i8) s += pst[wvl][mk][mh * 8 + i8];
            _Float16 hi, lo; split16(s * 0.125f, hi, lo);
            const size_t o = (size_t)(l + 1) * PM_STAGE + (size_t)b * 1024 + j * 64 + lane;
            pm_hi[o] = hi;
            pm_lo[o] = lo;
        }
    }
}

// ---------------------------------------------------------------------------
__device__ __forceinline__ void slogdet8(float M[8][8], float& sgn_out, float& ld_out) {
    float sgn = 1.f, ld = 0.f;
#pragma unroll
    for (int k = 0; k < 8; ++k) {
        float best = fabsf(M[k][k]);
        int p = k;
#pragma unroll
        for (int rr = k + 1; rr < 8; ++rr) {
            float v = fabsf(M[rr][k]);
            if (v > best) { best = v; p = rr; }
        }
        if (p != k) sgn = -sgn;
#pragma unroll
        for (int rr = k + 1; rr < 8; ++rr) {
            bool sw = (rr == p);
#pragma unroll
            for (int cc = k; cc < 8; ++cc) {
                float x = M[k][cc], y = M[rr][cc];
                M[k][cc]  = sw ? y : x;
                M[rr][cc] = sw ? x : y;
            }
        }
        float piv = M[k][k];
        if (piv < 0.f) sgn = -sgn;
        ld += logf(fabsf(piv));
        float inv = 1.f / piv;
#pragma unroll
        for (int rr = k + 1; rr < 8; ++rr) {
            float f = M[rr][k] * inv;
#pragma unroll
            for (int cc = k + 1; cc < 8; ++cc) M[rr][cc] -= f * M[k][cc];
        }
    }
    sgn_out = sgn; ld_out = ld;
}

// ---------------------------------------------------------------------------
// MEGA v14: R13-verbatim structure; only fast_tanh's div -> rcp*mul changed.
// ---------------------------------------------------------------------------
#define SROW 264
#define MROW 272

__global__ __launch_bounds__(1024, 4) void k_mega(
    const _Float16* __restrict__ pm_hi, const _Float16* __restrict__ pm_lo,
    const _Float16* __restrict__ Bhi, const _Float16* __restrict__ Blo,
    const _Float16* __restrict__ mBhi, const _Float16* __restrict__ mBlo,
    const float* __restrict__ sb, const float* __restrict__ vb,
    const float* __restrict__ sW0, const float* __restrict__ sb0,
    const float* __restrict__ r, const float* __restrict__ a,
    const _Float16* __restrict__ oBhi, const _Float16* __restrict__ oBlo,
    const float* __restrict__ wub, const float* __restrict__ wdb,
    const float* __restrict__ wfW,
    float* __restrict__ out)
{
    const int tid  = threadIdx.x;
    const int lane = tid & 63;
    const int wv   = tid >> 6;        // 0..15
    const int wg   = wv >> 2;         // walker pair group 0..3 (s-GEMM)
    const int wv4  = wv & 3;          // n-tile group (s-GEMM)
    const int m16  = lane & 15;
    const int quad = lane >> 4;
    const int b0   = blockIdx.x * 8;
    const int lw0  = wg * 2;          // local walkers lw0, lw0+1 (0..7)
    const int nb0  = wv4 * 64;

    __shared__ _Float16 sH[128][SROW];    // 67,584 B  [walker*16+e][k]
    __shared__ _Float16 sL[128][SROW];    // 67,584 B
    __shared__ _Float16 mH[16][MROW];     //  8,704 B  rows: mu w0..7, md w0..7
    __shared__ _Float16 mL[16][MROW];     //  8,704 B
    __shared__ float    ZshL[8][256];     //  8,192 B
    // total 160,768 B -> 1 block/CU, 16 waves

    // ========== prologue: fused k_s0 (embedding + first s layer, 8 walkers) ==
    {
        char*  sbase = (char*)&sH[0][0];
        float* pinA  = (float*)sbase;              // [8][16][16][4] 32,768 B (in sH)
        float* blkA  = (float*)(sbase + 32768);    // [8][16][56]    28,672 B (in sH)
        float* seA   = (float*)&ZshL[0][0];        // [8][16][16]     8,192 B (= ZshL)
        float* rlA   = (float*)&mH[0][0];          // [8][48] = 1,536 B
        float* alA   = rlA + 384;                  // [12]
        float* sm0A  = alA + 16;                   // [8][2][16] 1,024 B
        float* pm0A  = (float*)&mL[0][0];          // [8][16][2][4] 4,096 B

        if (tid < 384) rlA[tid] = r[(size_t)b0 * 48 + tid];
        if (tid >= 384 && tid < 396) alA[tid - 384] = a[tid - 384];
        __syncthreads();

#pragma unroll
        for (int it = 0; it < 2; ++it) {
            const int task = it * 1024 + tid;
            const int w = task >> 8, jj = (task >> 4) & 15, i = task & 15;
            const float* rw = rlA + w * 48;
            float dx = rw[jj * 3 + 0] - rw[i * 3 + 0];
            float dy = rw[jj * 3 + 1] - rw[i * 3 + 1];
            float dz = rw[jj * 3 + 2] - rw[i * 3 + 2];
            float ee = (i == jj) ? 1.0f : 0.0f;
            float len = sqrtf((dx + ee) * (dx + ee) + (dy + ee) * (dy + ee) + (dz + ee) * (dz + ee));
            float* p = pinA + (((w * 16 + jj) * 16 + i) << 2);
            p[0] = dx; p[1] = dy; p[2] = dz; p[3] = len;
        }
        if (tid < 128) {
            const int w = tid >> 4, e = tid & 15;
            const float* rw = rlA + w * 48;
#pragma unroll
            for (int at = 0; at < 4; ++at) {
                float dx = rw[e * 3 + 0] - alA[at * 3 + 0];
                float dy = rw[e * 3 + 1] - alA[at * 3 + 1];
                float dz = rw[e * 3 + 2] - alA[at * 3 + 2];
                float ln = sqrtf(dx * dx + dy * dy + dz * dz);
                float* p = seA + (w * 16 + e) * 16 + at * 4;
                p[0] = dx; p[1] = dy; p[2] = dz; p[3] = ln;
            }
        }
        __syncthreads();

        if (tid < 256) {
            const int w = tid >> 5, h = (tid >> 4) & 1, f = tid & 15;
            float s = 0.f;
            for (int e = 0; e < 8; ++e) s += seA[(w * 16 + h * 8 + e) * 16 + f];
            sm0A[(w * 2 + h) * 16 + f] = s * 0.125f;
        }
        {
            const int w = tid >> 7, jj = (tid >> 3) & 15, h = (tid >> 2) & 1, f = tid & 3;
            float s = 0.f;
            for (int i2 = 0; i2 < 8; ++i2)
                s += pinA[(((w * 16 + jj) * 16 + h * 8 + i2) << 2) + f];
            pm0A[((w * 16 + jj) * 2 + h) * 4 + f] = s * 0.125f;
        }
        __syncthreads();

        for (int t = tid; t < 8 * 16 * 56; t += 1024) {
            const int w = t / 896, rem = t % 896, e = rem / 56, k = rem % 56;
            float v;
            if (k < 16)      v = seA[(w * 16 + e) * 16 + k];
            else if (k < 32) v = sm0A[(w * 2 + 0) * 16 + (k - 16)];
            else if (k < 48) v = sm0A[(w * 2 + 1) * 16 + (k - 32)];
            else if (k < 52) v = pm0A[((w * 16 + e) * 2 + 0) * 4 + (k - 48)];
            else             v = pm0A[((w * 16 + e) * 2 + 1) * 4 + (k - 52)];
            blkA[(w * 16 + e) * 56 + k] = v;
        }
        __syncthreads();

        // GEMV (k_s0-identical per walker): thread = (col n0, walkers wsel/wsel+4)
        const int n0 = tid & 255, wsel = tid >> 8;   // 0..3
        float accA[16], accB[16];
#pragma unroll
        for (int e = 0; e < 16; ++e) { accA[e] = sb0[n0]; accB[e] = sb0[n0]; }
        for (int k = 0; k < 56; k += 4) {
            float w0 = sW0[(k + 0) * 256 + n0];
            float w1 = sW0[(k + 1) * 256 + n0];
            float w2 = sW0[(k + 2) * 256 + n0];
            float w3 = sW0[(k + 3) * 256 + n0];
#pragma unroll
            for (int e = 0; e < 16; ++e) {
                float4 sa = *(const float4*)&blkA[((wsel    ) * 16 + e) * 56 + k];
                float4 sc = *(const float4*)&blkA[((wsel + 4) * 16 + e) * 56 + k];
                accA[e] += sa.x * w0 + sa.y * w1 + sa.z * w2 + sa.w * w3;
                accB[e] += sc.x * w0 + sc.y * w1 + sc.z * w2 + sc.w * w3;
            }
        }
        __syncthreads();   // all blk/se reads complete before sH/sL overwrite

#pragma unroll
        for (int e = 0; e < 16; ++e) {
            _Float16 hi, lo;
            split16(fast_tanh(accA[e]), hi, lo);
            sH[wsel * 16 + e][n0] = hi;
            sL[wsel * 16 + e][n0] = lo;
            split16(fast_tanh(accB[e]), hi, lo);
            sH[(wsel + 4) * 16 + e][n0] = hi;
            sL[(wsel + 4) * 16 + e][n0] = lo;
        }
    }
    __syncthreads();

    // ========== means for layer 0 (reads rounded s) ==========
    {
        const int w  = tid >> 7;          // 0..7
        const int h  = (tid >> 6) & 1;
        const int k0 = (tid & 63) * 4;
        float s0 = 0.f, s1 = 0.f, s2 = 0.f, s3 = 0.f;
#pragma unroll
        for (int e = 0; e < 8; ++e) {
            const int row = w * 16 + h * 8 + e;
            f16x4 hv = *(const f16x4*)&sH[row][k0];
            f16x4 lv = *(const f16x4*)&sL[row][k0];
            s0 += (float)hv[0] + (float)lv[0];
            s1 += (float)hv[1] + (float)lv[1];
            s2 += (float)hv[2] + (float)lv[2];
            s3 += (float)hv[3] + (float)lv[3];
        }
        const int mrow = h * 8 + w;
        f16x4 hq, lq;
        _Float16 hi, lo;
        split16(s0 * 0.125f, hi, lo); hq[0] = hi; lq[0] = lo;
        split16(s1 * 0.125f, hi, lo); hq[1] = hi; lq[1] = lo;
        split16(s2 * 0.125f, hi, lo); hq[2] = hi; lq[2] = lo;
        split16(s3 * 0.125f, hi, lo); hq[3] = hi; lq[3] = lo;
        *(f16x4*)&mH[mrow][k0] = hq;
        *(f16x4*)&mL[mrow][k0] = lq;
    }
    __syncthreads();   // B1 (once)

    for (int l = 0; l < 5; ++l) {
        const float* bias = (l < 4) ? (sb + l * 256) : vb;
        const _Float16* pmH = pm_hi + (size_t)l * PM_STAGE;
        const _Float16* pmL = pm_lo + (size_t)l * PM_STAGE;
        const _Float16* Bh  = Bhi + (size_t)l * BPK_L;
        const _Float16* Bl  = Blo + (size_t)l * BPK_L;

        // ---- fused MFMA phase
        f32x4 acc[2][4];
        f32x4 macc0 = (f32x4){0.f, 0.f, 0.f, 0.f};   // mu chain
        f32x4 macc1 = (f32x4){0.f, 0.f, 0.f, 0.f};   // md chain
#pragma unroll
        for (int mt = 0; mt < 2; ++mt)
#pragma unroll
            for (int nt = 0; nt < 4; ++nt) acc[mt][nt] = (f32x4){0.f, 0.f, 0.f, 0.f};

        // -- PREFETCH pm A-frags (L3 latency hides under the MFMA loop)
        f16x8 pAh[2][2], pAl[2][2];   // [h][mt]
        {
            int aP[2];
#pragma unroll
            for (int mt = 0; mt < 2; ++mt)
                aP[mt] = ((b0 + lw0 + mt) * 16 + m16) * 64 + quad * 8;
#pragma unroll
            for (int h = 0; h < 2; ++h)
#pragma unroll
                for (int mt = 0; mt < 2; ++mt) {
                    pAh[h][mt] = *(const f16x8*)(pmH + aP[mt] + h * 32);
                    pAl[h][mt] = *(const f16x8*)(pmL + aP[mt] + h * 32);
                }
        }

        const _Float16* Bhw = Bh + (size_t)(wv4 * 4) * 512 + (size_t)lane * 8;
        const _Float16* Blw = Bl + (size_t)(wv4 * 4) * 512 + (size_t)lane * 8;
        const _Float16* mBh = mBhi + (size_t)l * MBK_L + (size_t)wv * 512 + (size_t)lane * 8;
        const _Float16* mBl = mBlo + (size_t)l * MBK_L + (size_t)wv * 512 + (size_t)lane * 8;
        const f16x8 z16 = (f16x8){0, 0, 0, 0, 0, 0, 0, 0};

#pragma unroll
        for (int kc = 0; kc < 8; ++kc) {
            // -- mean-GEMM sub-steps: independent mu/md accumulator chains
#pragma unroll
            for (int hh = 0; hh < 2; ++hh) {
                const int kk0  = kc * 32 + quad * 8;
                const int mrow = hh * 8 + (m16 & 7);
                f16x8 mah = *(const f16x8*)&mH[mrow][kk0];
                f16x8 mal = *(const f16x8*)&mL[mrow][kk0];
                if (m16 >= 8) { mah = z16; mal = z16; }
                const size_t mo = (size_t)(hh * 8 + kc) * 8192;
                f16x8 bh = *(const f16x8*)(mBh + mo);
                f16x8 bl = *(const f16x8*)(mBl + mo);
                if (hh == 0) {
                    macc0 = __builtin_amdgcn_mfma_f32_16x16x32_f16(mah, bh, macc0, 0, 0, 0);
                    macc0 = __builtin_amdgcn_mfma_f32_16x16x32_f16(mah, bl, macc0, 0, 0, 0);
                    macc0 = __builtin_amdgcn_mfma_f32_16x16x32_f16(mal, bh, macc0, 0, 0, 0);
                } else {
                    macc1 = __builtin_amdgcn_mfma_f32_16x16x32_f16(mah, bh, macc1, 0, 0, 0);
                    macc1 = __builtin_amdgcn_mfma_f32_16x16x32_f16(mah, bl, macc1, 0, 0, 0);
                    macc1 = __builtin_amdgcn_mfma_f32_16x16x32_f16(mal, bh, macc1, 0, 0, 0);
                }
            }
            // -- s-part step kc
            f16x8 ah[2], al[2];
#pragma unroll
            for (int mt = 0; mt < 2; ++mt) {
                const int row = (lw0 + mt) * 16 + m16;
                ah[mt] = *(const f16x8*)&sH[row][kc * 32 + quad * 8];
                al[mt] = *(const f16x8*)&sL[row][kc * 32 + quad * 8];
            }
#pragma unroll
            for (int nt = 0; nt < 4; ++nt) {
                f16x8 bh = *(const f16x8*)(Bhw + (size_t)kc * 8192 + nt * 512);
                f16x8 bl = *(const f16x8*)(Blw + (size_t)kc * 8192 + nt * 512);
#pragma unroll
                for (int mt = 0; mt < 2; ++mt) {
                    acc[mt][nt] = __builtin_amdgcn_mfma_f32_16x16x32_f16(ah[mt], bh, acc[mt][nt], 0, 0, 0);
                    acc[mt][nt] = __builtin_amdgcn_mfma_f32_16x16x32_f16(ah[mt], bl, acc[mt][nt], 0, 0, 0);
                    acc[mt][nt] = __builtin_amdgcn_mfma_f32_16x16x32_f16(al[mt], bh, acc[mt][nt], 0, 0, 0);
                }
            }
        }
        // -- p-part: kc 8..9 (pu, pd) from the prefetched registers
#pragma unroll
        for (int h = 0; h < 2; ++h) {
#pragma unroll
            for (int nt = 0; nt < 4; ++nt) {
                f16x8 bh = *(const f16x8*)(Bhw + (size_t)(8 + h) * 8192 + nt * 512);
                f16x8 bl = *(const f16x8*)(Blw + (size_t)(8 + h) * 8192 + nt * 512);
#pragma unroll
                for (int mt = 0; mt < 2; ++mt) {
                    acc[mt][nt] = __builtin_amdgcn_mfma_f32_16x16x32_f16(pAh[h][mt], bh, acc[mt][nt], 0, 0, 0);
                    acc[mt][nt] = __builtin_amdgcn_mfma_f32_16x16x32_f16(pAh[h][mt], bl, acc[mt][nt], 0, 0, 0);
                    acc[mt][nt] = __builtin_amdgcn_mfma_f32_16x16x32_f16(pAl[h][mt], bh, acc[mt][nt], 0, 0, 0);
                }
            }
        }
        // -- Z write: D rows 0..7 (quad 0,1) = walkers 0..7
        if (quad < 2) {
            const int n = wv * 16 + m16;
            const float bv = bias[n];
#pragma unroll
            for (int reg = 0; reg < 4; ++reg)
                ZshL[quad * 4 + reg][n] = bv + (macc0[reg] + macc1[reg]);
        }
        __syncthreads();   // B2: ZshL ready, all sH/sL/mH/mL reads complete

        // ---- epilogue (tanh + residual from LDS) with FUSED next-layer means
#pragma unroll
        for (int mt = 0; mt < 2; ++mt) {
#pragma unroll
            for (int nt = 0; nt < 4; ++nt) {
                const int n  = nb0 + nt * 16 + m16;
                const float zv = ZshL[lw0 + mt][n];
                float sum4 = 0.f;
#pragma unroll
                for (int reg = 0; reg < 4; ++reg) {
                    const int row = (lw0 + mt) * 16 + quad * 4 + reg;
                    float t = fast_tanh(acc[mt][nt][reg] + zv);
                    if (l != 4) t += (float)sH[row][n] + (float)sL[row][n];
                    sum4 += t;
                    _Float16 hi, lo; split16(t, hi, lo);
                    sH[row][n] = hi;
                    sL[row][n] = lo;
                }
                if (l != 4) {
                    float sum8 = sum4 + __shfl_xor(sum4, 16);
                    if ((quad & 1) == 0) {
                        const int mrow = (quad >> 1) * 8 + (lw0 + mt);
                        _Float16 hi, lo; split16(sum8 * 0.125f, hi, lo);
                        mH[mrow][n] = hi;
                        mL[mrow][n] = lo;
                    }
                }
            }
        }
        __syncthreads();   // B3: new s + means visible to next phase
    }

    // ======================= fused orbitals + slogdet =======================
    const int pg    = wv >> 2;        // walker pair 0..3
    const int ospin = (wv >> 1) & 1;
    const int nhalf = wv & 1;

    // envl -> aliased onto mH (means dead after layer-4 gemm)
    float* envp = (float*)&mH[0][0];      // [8][16]
    if (tid < 128) {
        const int w = tid >> 4, e = tid & 15;
        float ex = 0.f;
#pragma unroll
        for (int at = 0; at < 4; ++at) {
            float dx = r[(b0 + w) * 48 + e * 3 + 0] - a[at * 3 + 0];
            float dy = r[(b0 + w) * 48 + e * 3 + 1] - a[at * 3 + 1];
            float dz = r[(b0 + w) * 48 + e * 3 + 2] - a[at * 3 + 2];
            ex += __expf(-sqrtf(dx * dx + dy * dy + dz * dz));
        }
        envp[w * 16 + e] = ex;
    }

    // orbital GEMM: A rows from LDS s
    const int arow = (pg * 2 + (m16 >> 3)) * 16 + ospin * 8 + (m16 & 7);
    f32x4 oacc[4];
#pragma unroll
    for (int nt = 0; nt < 4; ++nt) oacc[nt] = (f32x4){0.f, 0.f, 0.f, 0.f};

#pragma unroll
    for (int kc = 0; kc < 8; ++kc) {
        f16x8 ah = *(const f16x8*)&sH[arow][kc * 32 + quad * 8];
        f16x8 al = *(const f16x8*)&sL[arow][kc * 32 + quad * 8];
#pragma unroll
        for (int nt = 0; nt < 4; ++nt) {
            const size_t bo = (((size_t)ospin * 8 + kc) * 8 + nhalf * 4 + nt) * 512 + (size_t)lane * 8;
            f16x8 bh = *(const f16x8*)(oBhi + bo);
            f16x8 bl = *(const f16x8*)(oBlo + bo);
            oacc[nt] = __builtin_amdgcn_mfma_f32_16x16x32_f16(ah, bh, oacc[nt], 0, 0, 0);
            oacc[nt] = __builtin_amdgcn_mfma_f32_16x16x32_f16(ah, bl, oacc[nt], 0, 0, 0);
            oacc[nt] = __builtin_amdgcn_mfma_f32_16x16x32_f16(al, bh, oacc[nt], 0, 0, 0);
            oacc[nt] = __builtin_amdgcn_mfma_f32_16x16x32_f16(al, bl, oacc[nt], 0, 0, 0);
        }
    }
    __syncthreads();   // all sH/sL A-reads + envl writes complete

    // scatter -> orbL aliased onto sH ([8][2][16][66] f32 = 67,584 B = exact fit)
    float* orbp = (float*)&sH[0][0];
    const float* bm = ospin ? wdb : wub;
#pragma unroll
    for (int nt = 0; nt < 4; ++nt) {
        const int c = nhalf * 64 + nt * 16 + m16;
        const float bv = bm[c];
        const int d = c & 15;
        const int jrow = c >> 4;
#pragma unroll
        for (int reg = 0; reg < 4; ++reg) {
            const int m = quad * 4 + reg;
            const int wl = pg * 2 + (m >> 3);
            const int el = m & 7;
            orbp[((wl * 2 + ospin) * 16 + d) * 66 + jrow * 8 + el] =
                (oacc[nt][reg] + bv) * envp[wl * 16 + ospin * 8 + el];
        }
    }
    __syncthreads();

    // determinants + lse: threads 0..127 = (walker w = tid>>4, det d = tid&15)
    if (tid < 128) {
        const int w = tid >> 4, d = tid & 15;
        float M[8][8];
#pragma unroll
        for (int rr = 0; rr < 8; ++rr)
#pragma unroll
            for (int cc = 0; cc < 8; ++cc)
                M[rr][cc] = orbp[((w * 2 + 0) * 16 + d) * 66 + rr * 8 + cc];
        float s1, l1; slogdet8(M, s1, l1);
#pragma unroll
        for (int rr = 0; rr < 8; ++rr)
#pragma unroll
            for (int cc = 0; cc < 8; ++cc)
                M[rr][cc] = orbp[((w * 2 + 1) * 16 + d) * 66 + rr * 8 + cc];
        float s2, l2; slogdet8(M, s2, l2);
        float sgn = s1 * s2;
        float ld  = l1 + l2;

        float m = ld;
        m = fmaxf(m, __shfl_xor(m, 1));
        m = fmaxf(m, __shfl_xor(m, 2));
        m = fmaxf(m, __shfl_xor(m, 4));
        m = fmaxf(m, __shfl_xor(m, 8));
        float sub = sgn * __expf(ld - m) * wfW[d];
        sub += __shfl_xor(sub, 1);
        sub += __shfl_xor(sub, 2);
        sub += __shfl_xor(sub, 4);
        sub += __shfl_xor(sub, 8);
        if (d == 0) out[b0 + w] = logf(fabsf(sub)) + m;
    }
}

// ---------------------------------------------------------------------------
extern "C" void kernel_launch(void* const* d_in, const int* in_sizes, int n_in,
                              void* d_out, int out_size, void* d_ws, size_t ws_size,
                              hipStream_t stream) {
    (void)in_sizes; (void)n_in; (void)out_size; (void)ws_size;
    const float* r   = (const float*)d_in[0];
    const float* a   = (const float*)d_in[1];
    const float* sW0 = (const float*)d_in[2];
    const float* sb0 = (const float*)d_in[3];
    const float* sW  = (const float*)d_in[4];
    const float* sb  = (const float*)d_in[5];
    const float* pW0 = (const float*)d_in[6];
    const float* pb0 = (const float*)d_in[7];
    const float* pW  = (const float*)d_in[8];
    const float* pb  = (const float*)d_in[9];
    const float* vW  = (const float*)d_in[10];
    const float* vb  = (const float*)d_in[11];
    const float* wuW = (const float*)d_in[12];
    const float* wub = (const float*)d_in[13];
    const float* wdW = (const float*)d_in[14];
    const float* wdb = (const float*)d_in[15];
    const float* wfW = (const float*)d_in[16];
    float* out = (float*)d_out;

    // workspace layout (bytes)
    char* wsb = (char*)d_ws;
    _Float16* pm_hi = (_Float16*)(wsb + 0);          // 20,971,520 (5 stages)
    _Float16* pm_lo = (_Float16*)(wsb + 20971520);   // 20,971,520
    _Float16* Bhi   = (_Float16*)(wsb + 41943040);   //    819,200
    _Float16* Blo   = (_Float16*)(wsb + 42762240);   //    819,200
    _Float16* pBhi  = (_Float16*)(wsb + 43581440);   //      8,192
    _Float16* pBlo  = (_Float16*)(wsb + 43589632);   //      8,192
    _Float16* oBhi  = (_Float16*)(wsb + 43597824);   //    131,072
    _Float16* oBlo  = (_Float16*)(wsb + 43728896);   //    131,072
    _Float16* mBhi  = (_Float16*)(wsb + 43859968);   //  1,310,720 (5 layers)
    _Float16* mBlo  = (_Float16*)(wsb + 45170688);   //  1,310,720
    // total 46,481,408 (< 79,691,776 known-safe)

    k_prep_all<<<556, 256, 0, stream>>>(sW, vW, pW, wuW, wdW,
                                        Bhi, Blo, pBhi, pBlo, oBhi, oBlo,
                                        mBhi, mBlo);
    k_pstream<<<NB * 4, 256, 0, stream>>>(r, pW0, pb0, pb, pBhi, pBlo, pm_hi, pm_lo);
    k_mega<<<NB / 8, 1024, 0, stream>>>(pm_hi, pm_lo, Bhi, Blo, mBhi, mBlo,
                                        sb, vb, sW0, sb0,
                                        r, a, oBhi, oBlo, wub, wdb, wfW, out);
}